// Round 4
// baseline (306.847 us; speedup 1.0000x reference)
//
#include <hip/hip_runtime.h>
#include <math.h>

#define EPS 1e-5f

// ---------------- workspace layout (floats) ----------------
// qkv   : 0          [7,340,032]  qkv, overwritten in-place with "so"
// Pq    : +7340032   [57,344]     partials: qkv [256][224], reused as sim [48][1024]
// prm   : +7397376   [560]        qkvP[256] | simP[48] | outP[256]
// tab   : +7397936   [2,240]      Rq/Rk/Sq/Sk window sums
// sumsO : +7400176   [256]        fallback out stats
// P2    : +7400448   [2,097,152]  out partials [256][8192] (only if ws big enough)

// =============== K0: window-sum tables from rel ===============
__global__ __launch_bounds__(256) void k_prep(const float* __restrict__ rel,
                                              float* __restrict__ tab) {
    __shared__ float r[16 * 111];
    for (int idx = threadIdx.x; idx < 1776; idx += 256) r[idx] = rel[idx];
    __syncthreads();
    for (int o = threadIdx.x; o < 2240; o += 256) {
        int row = o / 56, i = o - row * 56;
        float s = 0.f;
        if (row < 8) {
            const float* rr = &r[row * 111];
#pragma unroll
            for (int u = 0; u < 56; ++u) s += rr[i + u];
        } else if (row < 24) {
            int p = row - 8;
            const float* ra = &r[(p >> 2) * 111];
            const float* rb = &r[(p & 3) * 111];
#pragma unroll
            for (int u = 0; u < 56; ++u) s = fmaf(ra[i + u], rb[i + u], s);
        } else {
            int p = row - 24;
            const float* ra = &r[(4 + (p >> 2)) * 111];
            const float* rb = &r[(4 + (p & 3)) * 111];
#pragma unroll
            for (int u = 0; u < 56; ++u) s = fmaf(ra[i + u], rb[i + u], s);
        }
        tab[o] = s;
    }
}

// =============== K1: tiled GEMM, fused transpose-write + partial stats ===============
// grid 448: tile = bx%224, half = bx/224 selects oc range (2 blocks/CU, full machine)
__global__ __launch_bounds__(256) void k_qkv2(const float* __restrict__ x,
                                              const float* __restrict__ w,
                                              float* __restrict__ qkv,
                                              float* __restrict__ P) {
    __shared__ __align__(16) float X[64 * 256];
    __shared__ float T[8 * 264];
    const int t = threadIdx.x;
    const int tile = blockIdx.x % 224;
    const int half = blockIdx.x / 224;
    const int m0 = tile << 8;
    const int s = m0 / 1792;
    const int i0 = (m0 - s * 1792) >> 5;

    const float* xb = x + m0;
#pragma unroll
    for (int j = 0; j < 16; ++j) {
        int f = (j << 8) + t;
        int c = f >> 6, col = (f & 63) << 2;
        *(float4*)&X[(c << 8) + col] = *(const float4*)&xb[(size_t)c * 57344 + col];
    }
    __syncthreads();

    float* qb = qkv + (size_t)s * 229376 + i0;

    for (int oc = half * 8; oc < half * 8 + 8; ++oc) {
        const int o0 = oc << 3;
        const float* wp = w + (o0 << 6);
        float acc[8] = {0, 0, 0, 0, 0, 0, 0, 0};
        for (int c = 0; c < 64; ++c) {
            float xv = X[(c << 8) + t];
#pragma unroll
            for (int k = 0; k < 8; ++k) acc[k] = fmaf(wp[(k << 6) + c], xv, acc[k]);
        }
        __syncthreads();
#pragma unroll
        for (int k = 0; k < 8; ++k) T[k * 264 + t + (t >> 5)] = acc[k];
        __syncthreads();
#pragma unroll
        for (int e = 0; e < 8; ++e) {
            int flat = (e << 8) + t;
            int wcol = flat >> 6, oo = (flat >> 3) & 7, il = flat & 7;
            int mm = (il << 5) + wcol;
            qb[(size_t)wcol * 7168 + (o0 + oo) * 56 + il] = T[oo * 264 + mm + (mm >> 5)];
        }
        {
            int row = t >> 5, part = t & 31;
            float s1 = 0.f, s2 = 0.f;
#pragma unroll
            for (int e = 0; e < 8; ++e) {
                int mm = (part << 3) + e;
                float v = T[row * 264 + mm + (mm >> 5)];
                s1 += v; s2 += v * v;
            }
#pragma unroll
            for (int off = 16; off > 0; off >>= 1) {
                s1 += __shfl_xor(s1, off);
                s2 += __shfl_xor(s2, off);
            }
            if (part == 0) {
                P[(o0 + row) * 224 + tile] = s1;
                P[(128 + o0 + row) * 224 + tile] = s2;
            }
        }
    }
}

// =============== coalesced partial reduction -> BN params ===============
__global__ __launch_bounds__(64) void k_fin_red(const float* __restrict__ P,
                                                const float* __restrict__ g,
                                                const float* __restrict__ bb,
                                                float* __restrict__ prm,
                                                int nch, int npart, float invN) {
    const int c = blockIdx.x, lane = threadIdx.x;
    const float* r1 = P + (size_t)c * npart;
    const float* r2 = P + (size_t)(nch + c) * npart;
    float s1 = 0.f, s2 = 0.f;
    for (int p = lane; p < npart; p += 64) { s1 += r1[p]; s2 += r2[p]; }
#pragma unroll
    for (int off = 32; off > 0; off >>= 1) { s1 += __shfl_xor(s1, off); s2 += __shfl_xor(s2, off); }
    if (lane == 0) {
        float m = s1 * invN;
        float v = s2 * invN - m * m;
        float sc = g[c] * rsqrtf(v + EPS);
        prm[c] = sc;
        prm[nch + c] = bb[c] - m * sc;
    }
}

// =============== small finalize (fallback out BN) ===============
__global__ void k_fin(const float* __restrict__ sums, const float* __restrict__ g,
                      const float* __restrict__ bb, float* __restrict__ prm,
                      int nch, float invN) {
    int c = threadIdx.x;
    if (c >= nch) return;
    float m = sums[c] * invN;
    float v = sums[nch + c] * invN - m * m;
    float sc = g[c] * rsqrtf(v + EPS);
    prm[c] = sc;
    prm[nch + c] = bb[c] - m * sc;
}

// =============== K3: algebraic sim statistics (atomic-free) ===============
__global__ __launch_bounds__(256) void k_sim2(const float* __restrict__ qkv,
                                              const float* __restrict__ prmQ,
                                              const float* __restrict__ tab,
                                              float* __restrict__ P) {
    __shared__ float qn[8 * 8 * 57];
    __shared__ float T[40 * 57];
    __shared__ float red[8 * 6];
    const int t = threadIdx.x, b = blockIdx.x;

    const float* span = qkv + (size_t)b * 7168;
    for (int idx = t; idx < 3584; idx += 256) {
        int g = idx / 448, r = idx - g * 448, c = r / 56, i = r - c * 56;
        int ch = g * 16 + c;
        qn[(g * 8 + c) * 57 + i] = span[g * 896 + r] * prmQ[ch] + prmQ[128 + ch];
    }
    for (int idx = t; idx < 2240; idx += 256) {
        int row = idx / 56, i = idx - row * 56;
        int lr = (row < 8) ? (32 + row) : (row - 8);
        T[lr * 57 + i] = tab[idx];
    }
    __syncthreads();

    const int g = t >> 5, u = t & 31;
    const int half = (u < 16) ? 0 : 4;
    const float* rowA = &qn[g * 456 + (half + ((u >> 2) & 3)) * 57];
    const float* rowB = &qn[g * 456 + (half + (u & 3)) * 57];
    const float* tabS = &T[u * 57];
    const float* tabR = &T[(32 + half + (u & 3)) * 57];

    float gram = 0.f, wgt = 0.f, lin1 = 0.f, lin2 = 0.f;
#pragma unroll
    for (int i = 0; i < 56; ++i) {
        float a = rowA[i], b2 = rowB[i], p = a * b2;
        gram += p;
        wgt = fmaf(p, tabS[i], wgt);
        lin1 += b2;
        lin2 = fmaf(b2, tabR[i], lin2);
    }
    float linP = __shfl_xor(lin1, 16);
    float gramP = __shfl_xor(gram, 16);
    float v0 = (u < 4) ? lin1 * linP : 0.f;
    float v1 = (u < 16) ? gram * gramP : 0.f;
    float v2 = (u < 4) ? lin2 : 0.f;
    float v3 = (u < 16) ? wgt : 0.f;
    float v4 = (u >= 16 && u < 20) ? lin2 : 0.f;
    float v5 = (u >= 16) ? wgt : 0.f;
#pragma unroll
    for (int off = 16; off > 0; off >>= 1) {
        v0 += __shfl_xor(v0, off); v1 += __shfl_xor(v1, off);
        v2 += __shfl_xor(v2, off); v3 += __shfl_xor(v3, off);
        v4 += __shfl_xor(v4, off); v5 += __shfl_xor(v5, off);
    }
    if (u == 0) {
        red[g * 6 + 0] = v0; red[g * 6 + 1] = v1; red[g * 6 + 2] = v2;
        red[g * 6 + 3] = v3; red[g * 6 + 4] = v4; red[g * 6 + 5] = v5;
    }
    __syncthreads();
    if (t < 48) {
        int g2 = t / 6, s = t - g2 * 6;
        int row = ((s & 1) ? 24 : 0) + (s >> 1) * 8 + g2;
        P[(size_t)row * 1024 + b] = red[g2 * 6 + s];
    }
}

// =============== K5: fused QK/BN/softmax/PV, lane=column orientation ===============
__global__ __launch_bounds__(256) void k_main3(float* __restrict__ qkv,
                                               const float* __restrict__ rel,
                                               const float* __restrict__ prmQ,
                                               const float* __restrict__ prmS,
                                               float* __restrict__ P2,
                                               int useP2) {
    const int bg = blockIdx.x;
    const int g = bg & 7;
    __shared__ __align__(16) float qT[56 * 4];    // [i][c]
    __shared__ __align__(16) float kT[56 * 4];    // [j][c]
    __shared__ __align__(16) float vS[8 * 56];    // [c][j]
    __shared__ __align__(16) float rall[1776];    // rq[4][111] rk[4][111] rv[8][111]
    __shared__ float Pm[56 * 57];
    __shared__ float st[32];

    const int t = threadIdx.x;
    float* span = qkv + (size_t)bg * 896;

    // ---- stage: qkv span (BN'd) scattered to qT/kT/vS; rel copied flat ----
    if (t < 224) {
        int e0 = t * 4;
        int c = e0 / 56, i = e0 - c * 56;
        int ch = g * 16 + c;
        float sc = prmQ[ch], sh = prmQ[128 + ch];
        float4 vv = *(const float4*)&span[e0];
        float f0 = vv.x * sc + sh, f1 = vv.y * sc + sh;
        float f2 = vv.z * sc + sh, f3 = vv.w * sc + sh;
        if (c < 4) {
            qT[(i + 0) * 4 + c] = f0; qT[(i + 1) * 4 + c] = f1;
            qT[(i + 2) * 4 + c] = f2; qT[(i + 3) * 4 + c] = f3;
        } else if (c < 8) {
            int cc = c - 4;
            kT[(i + 0) * 4 + cc] = f0; kT[(i + 1) * 4 + cc] = f1;
            kT[(i + 2) * 4 + cc] = f2; kT[(i + 3) * 4 + cc] = f3;
        } else {
            float4 o; o.x = f0; o.y = f1; o.z = f2; o.w = f3;
            *(float4*)&vS[(c - 8) * 56 + i] = o;
        }
    }
    for (int idx = t; idx < 444; idx += 256)
        *(float4*)&rall[idx * 4] = *(const float4*)&rel[idx * 4];
    if (t < 32) st[t] = 0.f;
    __syncthreads();

    const int lane = t & 63, w = t >> 6;
    const int j = (lane < 56) ? lane : 0;
    const bool act = lane < 56;
    const float4 kf = *(const float4*)&kT[j * 4];

    const float sc_qk = prmS[g], sc_qr = prmS[8 + g], sc_kr = prmS[16 + g];
    const float sh_all = prmS[24 + g] + prmS[32 + g] + prmS[40 + g];
    const int i_base = w * 14;

    // ---- QK^T + BN + softmax (no-max: scores are BN-bounded), 2-row unroll ----
#pragma unroll
    for (int r = 0; r < 14; r += 2) {
        const int i0 = i_base + r;
        float4 qa = *(const float4*)&qT[i0 * 4];
        float4 qb = *(const float4*)&qT[(i0 + 1) * 4];
        const float* rqb = &rall[i0 - j + 55];
        const float* rkb = &rall[444 + j - i0 + 54];
        float qk0 = qa.x * kf.x + qa.y * kf.y + qa.z * kf.z + qa.w * kf.w;
        float qk1 = qb.x * kf.x + qb.y * kf.y + qb.z * kf.z + qb.w * kf.w;
        float qr0 = qa.x * rqb[0] + qa.y * rqb[111] + qa.z * rqb[222] + qa.w * rqb[333];
        float qr1 = qb.x * rqb[1] + qb.y * rqb[112] + qb.z * rqb[223] + qb.w * rqb[334];
        float kr0 = kf.x * rkb[1] + kf.y * rkb[112] + kf.z * rkb[223] + kf.w * rkb[334];
        float kr1 = kf.x * rkb[0] + kf.y * rkb[111] + kf.z * rkb[222] + kf.w * rkb[333];
        float s0 = qk0 * sc_qk + qr0 * sc_qr + kr0 * sc_kr + sh_all;
        float s1 = qk1 * sc_qk + qr1 * sc_qr + kr1 * sc_kr + sh_all;
        float e0 = act ? __expf(s0) : 0.f;
        float e1 = act ? __expf(s1) : 0.f;
        float t0 = e0, t1 = e1;
#pragma unroll
        for (int off = 32; off > 0; off >>= 1) {
            t0 += __shfl_xor(t0, off);
            t1 += __shfl_xor(t1, off);
        }
        float p0 = e0 * __builtin_amdgcn_rcpf(t0);
        float p1 = e1 * __builtin_amdgcn_rcpf(t1);
        if (act) {
            Pm[i0 * 57 + j] = p0;
            Pm[(i0 + 1) * 57 + j] = p1;
        }
    }
    // (no __syncthreads: each wave consumes only its own rows, LDS ops in-order)

    // ---- PV: lane -> (c, i) within this wave's rows ----
    const int il = lane % 14;
    const int cc = lane / 14;
    const bool pact = lane < 56;
    const int i = i_base + il;
#pragma unroll
    for (int pass = 0; pass < 2; ++pass) {
        int c = (cc < 4) ? (cc + (pass << 2)) : 0;
        const float* Pb = &Pm[i * 57];
        const float* vb = &vS[c * 56];
        const float* rvb = &rall[888 + c * 111 + i];
        float sv = 0.f, sve = 0.f;
        for (int jj = 0; jj < 56; jj += 2) {
            float p0 = Pb[jj], p1 = Pb[jj + 1];
            float v0 = vb[jj], v1 = vb[jj + 1];
            float r0 = rvb[55 - jj], r1 = rvb[54 - jj];
            sv = fmaf(p1, v1, fmaf(p0, v0, sv));
            sve = fmaf(p1, r1, fmaf(p0, r0, sve));
        }
        if (pact) {
            span[(c * 2) * 56 + i] = sv;
            span[(c * 2 + 1) * 56 + i] = sve;
            atomicAdd(&st[c * 2], sv);
            atomicAdd(&st[16 + c * 2], sv * sv);
            atomicAdd(&st[c * 2 + 1], sve);
            atomicAdd(&st[16 + c * 2 + 1], sve * sve);
        }
    }
    __syncthreads();
    if (t < 32) {
        int ch = g * 16 + (t & 15);
        int row = (t < 16) ? ch : (128 + ch);
        if (useP2) P2[(size_t)row * 8192 + bg] = st[t];
    }
}

// =============== fallback out stats ===============
__global__ __launch_bounds__(256) void k_stats(const float* __restrict__ so,
                                               float* __restrict__ sums) {
    const int t = threadIdx.x;
    const int o = blockIdx.x >> 3;
    const int b0 = (blockIdx.x & 7) << 7;
    float s1 = 0.f, s2 = 0.f;
#pragma unroll
    for (int j = 0; j < 7; ++j) {
        int f = (j << 8) + t;
        int row = f / 14, q = f - row * 14;
        const float* src = so + ((size_t)(b0 + row) * 128 + o) * 56 + (q << 2);
        float4 v = *(const float4*)src;
        s1 += v.x + v.y + v.z + v.w;
        s2 += v.x * v.x + v.y * v.y + v.z * v.z + v.w * v.w;
    }
#pragma unroll
    for (int off = 32; off > 0; off >>= 1) { s1 += __shfl_xor(s1, off); s2 += __shfl_xor(s2, off); }
    if ((t & 63) == 0) { atomicAdd(&sums[o], s1); atomicAdd(&sums[128 + o], s2); }
}

// =============== K7: out BN + channel-pair sum + transpose ===============
__global__ __launch_bounds__(256) void k_out2(const float* __restrict__ so,
                                              const float* __restrict__ prmO,
                                              float* __restrict__ out) {
    __shared__ float L[128 * 61];
    const int t = threadIdx.x;
    const int s = blockIdx.x & 31;
    const int pc = blockIdx.x >> 5;
    const int o0 = pc << 2;
    const int p0 = pc << 1;

#pragma unroll
    for (int j = 0; j < 7; ++j) {
        int f = (j << 8) + t;
        int row = f / 14, q = f - row * 14;
        int ch = row >> 5, wcol = row & 31;
        const float* src = so + ((size_t)(s * 32 + wcol) * 128 + o0 + ch) * 56 + (q << 2);
        float4 v = *(const float4*)src;
        float* dst = &L[row * 61 + (q << 2)];
        dst[0] = v.x; dst[1] = v.y; dst[2] = v.z; dst[3] = v.w;
    }
    __syncthreads();
#pragma unroll
    for (int j = 0; j < 14; ++j) {
        int flat = (j << 8) + t;
        int wcol = flat & 31, r = flat >> 5;
        int i = r % 56, pp = r / 56;
        float v0 = L[((pp * 2) * 32 + wcol) * 61 + i];
        float v1 = L[((pp * 2 + 1) * 32 + wcol) * 61 + i];
        float sc0 = prmO[o0 + (pp << 1)],     sh0 = prmO[128 + o0 + (pp << 1)];
        float sc1 = prmO[o0 + (pp << 1) + 1], sh1 = prmO[128 + o0 + (pp << 1) + 1];
        out[(((size_t)(p0 + pp) * 32 + s) * 56 + i) * 32 + wcol] =
            v0 * sc0 + sh0 + v1 * sc1 + sh1;
    }
}

extern "C" void kernel_launch(void* const* d_in, const int* in_sizes, int n_in,
                              void* d_out, int out_size, void* d_ws, size_t ws_size,
                              hipStream_t stream) {
    const float* x     = (const float*)d_in[0];
    const float* w_qkv = (const float*)d_in[1];
    const float* g_qkv = (const float*)d_in[2];
    const float* b_qkv = (const float*)d_in[3];
    const float* g_sim = (const float*)d_in[4];
    const float* b_sim = (const float*)d_in[5];
    const float* g_out = (const float*)d_in[6];
    const float* b_out = (const float*)d_in[7];
    const float* rel   = (const float*)d_in[8];
    float* out = (float*)d_out;

    float* ws    = (float*)d_ws;
    float* qkv   = ws;
    float* Pq    = ws + 7340032;
    float* prm   = ws + 7397376;
    float* tab   = ws + 7397936;
    float* sumsO = ws + 7400176;
    float* P2    = ws + 7400448;
    const bool big = ws_size >= (size_t)(7400448 + 2097152) * sizeof(float);

    k_prep<<<1, 256, 0, stream>>>(rel, tab);
    k_qkv2<<<448, 256, 0, stream>>>(x, w_qkv, qkv, Pq);
    k_fin_red<<<128, 64, 0, stream>>>(Pq, g_qkv, b_qkv, prm, 128, 224, 1.f / 57344.f);
    k_sim2<<<1024, 256, 0, stream>>>(qkv, prm, tab, Pq);
    k_fin_red<<<24, 64, 0, stream>>>(Pq, g_sim, b_sim, prm + 256, 24, 1024, 1.f / 3211264.f);

    if (big) {
        k_main3<<<8192, 256, 0, stream>>>(qkv, rel, prm, prm + 256, P2, 1);
        k_fin_red<<<128, 64, 0, stream>>>(P2, g_out, b_out, prm + 304, 128, 8192, 1.f / 57344.f);
    } else {
        hipMemsetAsync(sumsO, 0, 256 * sizeof(float), stream);
        k_main3<<<8192, 256, 0, stream>>>(qkv, rel, prm, prm + 256, sumsO, 0);
        k_stats<<<1024, 256, 0, stream>>>(qkv, sumsO);
        k_fin<<<1, 128, 0, stream>>>(sumsO, g_out, b_out, prm + 304, 128, 1.f / 57344.f);
    }
    k_out2<<<1024, 256, 0, stream>>>(qkv, prm + 304, out);
}

// Round 5
// 195.990 us; speedup vs baseline: 1.5656x; 1.5656x over previous
//
#include <hip/hip_runtime.h>
#include <math.h>

#define EPS 1e-5f

// ---------------- workspace layout (floats) ----------------
// qkv   : 0          [7,340,032]  qkv, overwritten in-place with "so"
// Pq    : +7340032   [57,344]     partials: qkv [256][224], reused as sim [48][1024]
// prm   : +7397376   [560]        qkvP[256] | simP[48] | outP[256]
// tab   : +7397936   [2,240]      Rq/Rk/Sq/Sk window sums
// sumsO : +7400176   [256]        fallback out stats
// P2    : +7400448   [2,097,152]  out partials [256][8192] (only if ws big enough)

// =============== K0: window-sum tables from rel ===============
__global__ __launch_bounds__(256) void k_prep(const float* __restrict__ rel,
                                              float* __restrict__ tab) {
    __shared__ float r[16 * 111];
    for (int idx = threadIdx.x; idx < 1776; idx += 256) r[idx] = rel[idx];
    __syncthreads();
    for (int o = threadIdx.x; o < 2240; o += 256) {
        int row = o / 56, i = o - row * 56;
        float s = 0.f;
        if (row < 8) {
            const float* rr = &r[row * 111];
#pragma unroll
            for (int u = 0; u < 56; ++u) s += rr[i + u];
        } else if (row < 24) {
            int p = row - 8;
            const float* ra = &r[(p >> 2) * 111];
            const float* rb = &r[(p & 3) * 111];
#pragma unroll
            for (int u = 0; u < 56; ++u) s = fmaf(ra[i + u], rb[i + u], s);
        } else {
            int p = row - 24;
            const float* ra = &r[(4 + (p >> 2)) * 111];
            const float* rb = &r[(4 + (p & 3)) * 111];
#pragma unroll
            for (int u = 0; u < 56; ++u) s = fmaf(ra[i + u], rb[i + u], s);
        }
        tab[o] = s;
    }
}

// =============== K1: tiled GEMM, fused transpose-write + partial stats ===============
__global__ __launch_bounds__(256) void k_qkv2(const float* __restrict__ x,
                                              const float* __restrict__ w,
                                              float* __restrict__ qkv,
                                              float* __restrict__ P) {
    __shared__ __align__(16) float X[64 * 256];
    __shared__ float T[8 * 264];
    const int t = threadIdx.x;
    const int tile = blockIdx.x % 224;
    const int half = blockIdx.x / 224;
    const int m0 = tile << 8;
    const int s = m0 / 1792;
    const int i0 = (m0 - s * 1792) >> 5;

    const float* xb = x + m0;
#pragma unroll
    for (int j = 0; j < 16; ++j) {
        int f = (j << 8) + t;
        int c = f >> 6, col = (f & 63) << 2;
        *(float4*)&X[(c << 8) + col] = *(const float4*)&xb[(size_t)c * 57344 + col];
    }
    __syncthreads();

    float* qb = qkv + (size_t)s * 229376 + i0;

    for (int oc = half * 8; oc < half * 8 + 8; ++oc) {
        const int o0 = oc << 3;
        const float* wp = w + (o0 << 6);
        float acc[8] = {0, 0, 0, 0, 0, 0, 0, 0};
        for (int c = 0; c < 64; ++c) {
            float xv = X[(c << 8) + t];
#pragma unroll
            for (int k = 0; k < 8; ++k) acc[k] = fmaf(wp[(k << 6) + c], xv, acc[k]);
        }
        __syncthreads();
#pragma unroll
        for (int k = 0; k < 8; ++k) T[k * 264 + t + (t >> 5)] = acc[k];
        __syncthreads();
#pragma unroll
        for (int e = 0; e < 8; ++e) {
            int flat = (e << 8) + t;
            int wcol = flat >> 6, oo = (flat >> 3) & 7, il = flat & 7;
            int mm = (il << 5) + wcol;
            qb[(size_t)wcol * 7168 + (o0 + oo) * 56 + il] = T[oo * 264 + mm + (mm >> 5)];
        }
        {
            int row = t >> 5, part = t & 31;
            float s1 = 0.f, s2 = 0.f;
#pragma unroll
            for (int e = 0; e < 8; ++e) {
                int mm = (part << 3) + e;
                float v = T[row * 264 + mm + (mm >> 5)];
                s1 += v; s2 += v * v;
            }
#pragma unroll
            for (int off = 16; off > 0; off >>= 1) {
                s1 += __shfl_xor(s1, off);
                s2 += __shfl_xor(s2, off);
            }
            if (part == 0) {
                P[(o0 + row) * 224 + tile] = s1;
                P[(128 + o0 + row) * 224 + tile] = s2;
            }
        }
    }
}

// =============== coalesced partial reduction -> BN params ===============
__global__ __launch_bounds__(64) void k_fin_red(const float* __restrict__ P,
                                                const float* __restrict__ g,
                                                const float* __restrict__ bb,
                                                float* __restrict__ prm,
                                                int nch, int npart, float invN) {
    const int c = blockIdx.x, lane = threadIdx.x;
    const float* r1 = P + (size_t)c * npart;
    const float* r2 = P + (size_t)(nch + c) * npart;
    float s1 = 0.f, s2 = 0.f;
    for (int p = lane; p < npart; p += 64) { s1 += r1[p]; s2 += r2[p]; }
#pragma unroll
    for (int off = 32; off > 0; off >>= 1) { s1 += __shfl_xor(s1, off); s2 += __shfl_xor(s2, off); }
    if (lane == 0) {
        float m = s1 * invN;
        float v = s2 * invN - m * m;
        float sc = g[c] * rsqrtf(v + EPS);
        prm[c] = sc;
        prm[nch + c] = bb[c] - m * sc;
    }
}

// =============== small finalize (fallback out BN) ===============
__global__ void k_fin(const float* __restrict__ sums, const float* __restrict__ g,
                      const float* __restrict__ bb, float* __restrict__ prm,
                      int nch, float invN) {
    int c = threadIdx.x;
    if (c >= nch) return;
    float m = sums[c] * invN;
    float v = sums[nch + c] * invN - m * m;
    float sc = g[c] * rsqrtf(v + EPS);
    prm[c] = sc;
    prm[nch + c] = bb[c] - m * sc;
}

// =============== K3: algebraic sim statistics (atomic-free) ===============
__global__ __launch_bounds__(256) void k_sim2(const float* __restrict__ qkv,
                                              const float* __restrict__ prmQ,
                                              const float* __restrict__ tab,
                                              float* __restrict__ P) {
    __shared__ float qn[8 * 8 * 57];
    __shared__ float T[40 * 57];
    __shared__ float red[8 * 6];
    const int t = threadIdx.x, b = blockIdx.x;

    const float* span = qkv + (size_t)b * 7168;
    for (int idx = t; idx < 3584; idx += 256) {
        int g = idx / 448, r = idx - g * 448, c = r / 56, i = r - c * 56;
        int ch = g * 16 + c;
        qn[(g * 8 + c) * 57 + i] = span[g * 896 + r] * prmQ[ch] + prmQ[128 + ch];
    }
    for (int idx = t; idx < 2240; idx += 256) {
        int row = idx / 56, i = idx - row * 56;
        int lr = (row < 8) ? (32 + row) : (row - 8);
        T[lr * 57 + i] = tab[idx];
    }
    __syncthreads();

    const int g = t >> 5, u = t & 31;
    const int half = (u < 16) ? 0 : 4;
    const float* rowA = &qn[g * 456 + (half + ((u >> 2) & 3)) * 57];
    const float* rowB = &qn[g * 456 + (half + (u & 3)) * 57];
    const float* tabS = &T[u * 57];
    const float* tabR = &T[(32 + half + (u & 3)) * 57];

    float gram = 0.f, wgt = 0.f, lin1 = 0.f, lin2 = 0.f;
#pragma unroll
    for (int i = 0; i < 56; ++i) {
        float a = rowA[i], b2 = rowB[i], p = a * b2;
        gram += p;
        wgt = fmaf(p, tabS[i], wgt);
        lin1 += b2;
        lin2 = fmaf(b2, tabR[i], lin2);
    }
    float linP = __shfl_xor(lin1, 16);
    float gramP = __shfl_xor(gram, 16);
    float v0 = (u < 4) ? lin1 * linP : 0.f;
    float v1 = (u < 16) ? gram * gramP : 0.f;
    float v2 = (u < 4) ? lin2 : 0.f;
    float v3 = (u < 16) ? wgt : 0.f;
    float v4 = (u >= 16 && u < 20) ? lin2 : 0.f;
    float v5 = (u >= 16) ? wgt : 0.f;
#pragma unroll
    for (int off = 16; off > 0; off >>= 1) {
        v0 += __shfl_xor(v0, off); v1 += __shfl_xor(v1, off);
        v2 += __shfl_xor(v2, off); v3 += __shfl_xor(v3, off);
        v4 += __shfl_xor(v4, off); v5 += __shfl_xor(v5, off);
    }
    if (u == 0) {
        red[g * 6 + 0] = v0; red[g * 6 + 1] = v1; red[g * 6 + 2] = v2;
        red[g * 6 + 3] = v3; red[g * 6 + 4] = v4; red[g * 6 + 5] = v5;
    }
    __syncthreads();
    if (t < 48) {
        int g2 = t / 6, s = t - g2 * 6;
        int row = ((s & 1) ? 24 : 0) + (s >> 1) * 8 + g2;
        P[(size_t)row * 1024 + b] = red[g2 * 6 + s];
    }
}

// =============== K5: fused QK/BN/exp -> PV with inline rowsum, no shuffles/atomics ===============
__global__ __launch_bounds__(256) void k_main4(float* __restrict__ qkv,
                                               const float* __restrict__ rel,
                                               const float* __restrict__ prmQ,
                                               const float* __restrict__ prmS,
                                               float* __restrict__ P2,
                                               int useP2) {
    const int bg = blockIdx.x;
    const int g = bg & 7;
    __shared__ __align__(16) float S[16 * 60];    // q rows 0-3, k 4-7, v 8-15 (pad 60)
    __shared__ __align__(16) float rall[1776];    // rq[4][111] rk[4][111] rv[8][111]
    __shared__ float Pm[56 * 57];                 // raw exp values
    __shared__ float red[128];                    // [pass*4+cc][val][wave]

    const int t = threadIdx.x;
    float* span = qkv + (size_t)bg * 896;

    // ---- stage: BN'd q/k/v into S rows (aligned float4, <=2-way bank alias) ----
    if (t < 224) {
        int e0 = t * 4;
        int c = e0 / 56, i = e0 - c * 56;
        int ch = g * 16 + c;
        float sc = prmQ[ch], sh = prmQ[128 + ch];
        float4 vv = *(const float4*)&span[e0];
        float4 o;
        o.x = vv.x * sc + sh; o.y = vv.y * sc + sh;
        o.z = vv.z * sc + sh; o.w = vv.w * sc + sh;
        *(float4*)&S[c * 60 + i] = o;
    }
    for (int idx = t; idx < 444; idx += 256)
        *(float4*)&rall[idx * 4] = *(const float4*)&rel[idx * 4];
    __syncthreads();

    const int lane = t & 63, w = t >> 6;
    const int i_base = w * 14;
    const bool act = lane < 56;
    const int j = act ? lane : 0;

    // k fragment: 4 stride-1 b32 reads, conflict-free
    const float k0 = S[4 * 60 + j], k1 = S[5 * 60 + j];
    const float k2 = S[6 * 60 + j], k3 = S[7 * 60 + j];

    const float sc_qk = prmS[g], sc_qr = prmS[8 + g], sc_kr = prmS[16 + g];
    const float sh_all = prmS[24 + g] + prmS[32 + g] + prmS[40 + g];

    // ---- scores + exp, write RAW e to Pm (normalization deferred to PV) ----
    for (int r = 0; r < 14; r += 2) {
        const int i0 = i_base + r;
        float qa0 = S[i0], qa1 = S[60 + i0], qa2 = S[120 + i0], qa3 = S[180 + i0];
        float qb0 = S[i0 + 1], qb1 = S[60 + i0 + 1], qb2 = S[120 + i0 + 1], qb3 = S[180 + i0 + 1];
        const float* rq = &rall[i0 - j + 55];
        const float* rk = &rall[444 + j - i0 + 54];
        float qk0 = qa0 * k0 + qa1 * k1 + qa2 * k2 + qa3 * k3;
        float qk1 = qb0 * k0 + qb1 * k1 + qb2 * k2 + qb3 * k3;
        float qr0 = qa0 * rq[0] + qa1 * rq[111] + qa2 * rq[222] + qa3 * rq[333];
        float qr1 = qb0 * rq[1] + qb1 * rq[112] + qb2 * rq[223] + qb3 * rq[334];
        float kr0 = k0 * rk[1] + k1 * rk[112] + k2 * rk[223] + k3 * rk[334];
        float kr1 = k0 * rk[0] + k1 * rk[111] + k2 * rk[222] + k3 * rk[333];
        float s0 = qk0 * sc_qk + qr0 * sc_qr + kr0 * sc_kr + sh_all;
        float s1 = qk1 * sc_qk + qr1 * sc_qr + kr1 * sc_kr + sh_all;
        float e0 = act ? __expf(s0) : 0.f;
        float e1 = act ? __expf(s1) : 0.f;
        if (act) {
            Pm[i0 * 57 + j] = e0;
            Pm[(i0 + 1) * 57 + j] = e1;
        }
    }
    // no __syncthreads: each wave consumes only its own rows (in-order DS pipe)

    // ---- PV with inline rowsum; lane = 16-aligned (cc, il) ----
    const int il = lane & 15, cc = lane >> 4;
    const bool pact = il < 14;
    const int i = pact ? (i_base + il) : i_base;

#pragma unroll
    for (int pass = 0; pass < 2; ++pass) {
        const int c = cc + (pass << 2);            // v-channel 0..7
        const float* Pb = &Pm[i * 57];
        const float* vb = &S[(8 + c) * 60];
        const float* rvb = &rall[888 + c * 111 + i];
        float sv = 0.f, sve = 0.f, rs = 0.f;
        for (int jj = 0; jj < 56; jj += 2) {
            float p0 = Pb[jj], p1 = Pb[jj + 1];
            float v0 = vb[jj], v1 = vb[jj + 1];
            float r0 = rvb[55 - jj], r1 = rvb[54 - jj];
            sv = fmaf(p1, v1, fmaf(p0, v0, sv));
            sve = fmaf(p1, r1, fmaf(p0, r0, sve));
            rs += p0 + p1;
        }
        float inv = __builtin_amdgcn_rcpf(rs);
        sv *= inv; sve *= inv;
        if (pact) {
            span[(c * 2) * 56 + i] = sv;
            span[(c * 2 + 1) * 56 + i] = sve;
        }
        // register stats reduction within each aligned 16-lane group
        float a0 = pact ? sv : 0.f,  a1 = pact ? sv * sv : 0.f;
        float a2 = pact ? sve : 0.f, a3 = pact ? sve * sve : 0.f;
#pragma unroll
        for (int off = 8; off > 0; off >>= 1) {
            a0 += __shfl_xor(a0, off); a1 += __shfl_xor(a1, off);
            a2 += __shfl_xor(a2, off); a3 += __shfl_xor(a3, off);
        }
        if (il == 0) {
            int base = ((pass * 4 + cc) * 4) * 4 + w;
            red[base + 0]  = a0;
            red[base + 4]  = a1;
            red[base + 8]  = a2;
            red[base + 12] = a3;
        }
    }
    __syncthreads();
    if (useP2 && t < 32) {
        // t = (pass*4+cc)*4 + v ; v: 0=sv_sum 1=sv_sq 2=sve_sum 3=sve_sq
        float s = red[t * 4] + red[t * 4 + 1] + red[t * 4 + 2] + red[t * 4 + 3];
        int pass = t >> 4, cc2 = (t >> 2) & 3, v = t & 3;
        int c = cc2 + (pass << 2);
        int ch = g * 16 + c * 2 + (v >> 1);
        int row = (v & 1) ? (128 + ch) : ch;
        P2[(size_t)row * 8192 + bg] = s;
    }
}

// =============== fallback out stats ===============
__global__ __launch_bounds__(256) void k_stats(const float* __restrict__ so,
                                               float* __restrict__ sums) {
    const int t = threadIdx.x;
    const int o = blockIdx.x >> 3;
    const int b0 = (blockIdx.x & 7) << 7;
    float s1 = 0.f, s2 = 0.f;
#pragma unroll
    for (int j = 0; j < 7; ++j) {
        int f = (j << 8) + t;
        int row = f / 14, q = f - row * 14;
        const float* src = so + ((size_t)(b0 + row) * 128 + o) * 56 + (q << 2);
        float4 v = *(const float4*)src;
        s1 += v.x + v.y + v.z + v.w;
        s2 += v.x * v.x + v.y * v.y + v.z * v.z + v.w * v.w;
    }
#pragma unroll
    for (int off = 32; off > 0; off >>= 1) { s1 += __shfl_xor(s1, off); s2 += __shfl_xor(s2, off); }
    if ((t & 63) == 0) { atomicAdd(&sums[o], s1); atomicAdd(&sums[128 + o], s2); }
}

// =============== K7: out BN + channel-pair sum + transpose ===============
__global__ __launch_bounds__(256) void k_out2(const float* __restrict__ so,
                                              const float* __restrict__ prmO,
                                              float* __restrict__ out) {
    __shared__ float L[128 * 61];
    const int t = threadIdx.x;
    const int s = blockIdx.x & 31;
    const int pc = blockIdx.x >> 5;
    const int o0 = pc << 2;
    const int p0 = pc << 1;

#pragma unroll
    for (int j = 0; j < 7; ++j) {
        int f = (j << 8) + t;
        int row = f / 14, q = f - row * 14;
        int ch = row >> 5, wcol = row & 31;
        const float* src = so + ((size_t)(s * 32 + wcol) * 128 + o0 + ch) * 56 + (q << 2);
        float4 v = *(const float4*)src;
        float* dst = &L[row * 61 + (q << 2)];
        dst[0] = v.x; dst[1] = v.y; dst[2] = v.z; dst[3] = v.w;
    }
    __syncthreads();
#pragma unroll
    for (int j = 0; j < 14; ++j) {
        int flat = (j << 8) + t;
        int wcol = flat & 31, r = flat >> 5;
        int i = r % 56, pp = r / 56;
        float v0 = L[((pp * 2) * 32 + wcol) * 61 + i];
        float v1 = L[((pp * 2 + 1) * 32 + wcol) * 61 + i];
        float sc0 = prmO[o0 + (pp << 1)],     sh0 = prmO[128 + o0 + (pp << 1)];
        float sc1 = prmO[o0 + (pp << 1) + 1], sh1 = prmO[128 + o0 + (pp << 1) + 1];
        out[(((size_t)(p0 + pp) * 32 + s) * 56 + i) * 32 + wcol] =
            v0 * sc0 + sh0 + v1 * sc1 + sh1;
    }
}

extern "C" void kernel_launch(void* const* d_in, const int* in_sizes, int n_in,
                              void* d_out, int out_size, void* d_ws, size_t ws_size,
                              hipStream_t stream) {
    const float* x     = (const float*)d_in[0];
    const float* w_qkv = (const float*)d_in[1];
    const float* g_qkv = (const float*)d_in[2];
    const float* b_qkv = (const float*)d_in[3];
    const float* g_sim = (const float*)d_in[4];
    const float* b_sim = (const float*)d_in[5];
    const float* g_out = (const float*)d_in[6];
    const float* b_out = (const float*)d_in[7];
    const float* rel   = (const float*)d_in[8];
    float* out = (float*)d_out;

    float* ws    = (float*)d_ws;
    float* qkv   = ws;
    float* Pq    = ws + 7340032;
    float* prm   = ws + 7397376;
    float* tab   = ws + 7397936;
    float* sumsO = ws + 7400176;
    float* P2    = ws + 7400448;
    const bool big = ws_size >= (size_t)(7400448 + 2097152) * sizeof(float);

    k_prep<<<1, 256, 0, stream>>>(rel, tab);
    k_qkv2<<<448, 256, 0, stream>>>(x, w_qkv, qkv, Pq);
    k_fin_red<<<128, 64, 0, stream>>>(Pq, g_qkv, b_qkv, prm, 128, 224, 1.f / 57344.f);
    k_sim2<<<1024, 256, 0, stream>>>(qkv, prm, tab, Pq);
    k_fin_red<<<24, 64, 0, stream>>>(Pq, g_sim, b_sim, prm + 256, 24, 1024, 1.f / 3211264.f);

    if (big) {
        k_main4<<<8192, 256, 0, stream>>>(qkv, rel, prm, prm + 256, P2, 1);
        k_fin_red<<<128, 64, 0, stream>>>(P2, g_out, b_out, prm + 304, 128, 8192, 1.f / 57344.f);
    } else {
        hipMemsetAsync(sumsO, 0, 256 * sizeof(float), stream);
        k_main4<<<8192, 256, 0, stream>>>(qkv, rel, prm, prm + 256, sumsO, 0);
        k_stats<<<1024, 256, 0, stream>>>(qkv, sumsO);
        k_fin<<<1, 128, 0, stream>>>(sumsO, g_out, b_out, prm + 304, 128, 1.f / 57344.f);
    }
    k_out2<<<1024, 256, 0, stream>>>(qkv, prm + 304, out);
}

// Round 6
// 143.909 us; speedup vs baseline: 2.1322x; 1.3619x over previous
//
#include <hip/hip_runtime.h>
#include <math.h>

#define EPS 1e-5f

typedef float f32x2 __attribute__((ext_vector_type(2)));
typedef float f32x4 __attribute__((ext_vector_type(4)));
__device__ __forceinline__ f32x2 fma2(f32x2 a, f32x2 b, f32x2 c) {
    return __builtin_elementwise_fma(a, b, c);
}
__device__ __forceinline__ f32x4 fma4(f32x4 a, f32x4 b, f32x4 c) {
    return __builtin_elementwise_fma(a, b, c);
}
__device__ __forceinline__ f32x2 sp2(float x) { f32x2 r = {x, x}; return r; }

// ---------------- workspace layout (floats) ----------------
// qkv   : 0          [7,340,032]  qkv, overwritten in-place with "so"
// Pq    : +7340032   [57,344]     partials: qkv [256][224], reused as sim [48][1024]
// prm   : +7397376   [560]        qkvP[256] | simP[48] | outP[256]
// tab   : +7397936   [2,240]      Rq/Rk/Sq/Sk window sums
// sumsO : +7400176   [256]        fallback out stats
// P2    : +7400448   [2,097,152]  out partials [256][8192] (only if ws big enough)

// =============== K1: tiled GEMM (packed fp32) + transpose-write + stats;
//                 block 448 computes the rel window-sum tables ===============
__global__ __launch_bounds__(256) void k_qkv2(const float* __restrict__ x,
                                              const float* __restrict__ w,
                                              const float* __restrict__ rel,
                                              float* __restrict__ qkv,
                                              float* __restrict__ P,
                                              float* __restrict__ tab) {
    __shared__ __align__(16) float X[64 * 256];
    __shared__ float T[8 * 264];
    const int t = threadIdx.x;

    if (blockIdx.x == 448) {            // ---- prep path: window-sum tables ----
        float* r = X;                   // reuse X as scratch
        for (int idx = t; idx < 1776; idx += 256) r[idx] = rel[idx];
        __syncthreads();
        for (int o = t; o < 2240; o += 256) {
            int row = o / 56, i = o - row * 56;
            float s = 0.f;
            if (row < 8) {
                const float* rr = &r[row * 111];
#pragma unroll
                for (int u = 0; u < 56; ++u) s += rr[i + u];
            } else if (row < 24) {
                int p = row - 8;
                const float* ra = &r[(p >> 2) * 111];
                const float* rb = &r[(p & 3) * 111];
#pragma unroll
                for (int u = 0; u < 56; ++u) s = fmaf(ra[i + u], rb[i + u], s);
            } else {
                int p = row - 24;
                const float* ra = &r[(4 + (p >> 2)) * 111];
                const float* rb = &r[(4 + (p & 3)) * 111];
#pragma unroll
                for (int u = 0; u < 56; ++u) s = fmaf(ra[i + u], rb[i + u], s);
            }
            tab[o] = s;
        }
        return;
    }

    const int tile = blockIdx.x % 224;
    const int half = blockIdx.x / 224;
    const int m0 = tile << 8;
    const int s = m0 / 1792;
    const int i0 = (m0 - s * 1792) >> 5;

    const float* xb = x + m0;
#pragma unroll
    for (int j = 0; j < 16; ++j) {
        int f = (j << 8) + t;
        int c = f >> 6, col = (f & 63) << 2;
        *(float4*)&X[(c << 8) + col] = *(const float4*)&xb[(size_t)c * 57344 + col];
    }
    __syncthreads();

    float* qb = qkv + (size_t)s * 229376 + i0;

    for (int oc = half * 8; oc < half * 8 + 8; ++oc) {
        const int o0 = oc << 3;
        const float* wp = w + (o0 << 6);
        f32x2 a01 = {0, 0}, a23 = {0, 0}, a45 = {0, 0}, a67 = {0, 0};
        for (int c = 0; c < 64; ++c) {
            float xv = X[(c << 8) + t];
            f32x2 w01 = {wp[c], wp[64 + c]};
            f32x2 w23 = {wp[128 + c], wp[192 + c]};
            f32x2 w45 = {wp[256 + c], wp[320 + c]};
            f32x2 w67 = {wp[384 + c], wp[448 + c]};
            f32x2 xs = sp2(xv);
            a01 = fma2(w01, xs, a01);
            a23 = fma2(w23, xs, a23);
            a45 = fma2(w45, xs, a45);
            a67 = fma2(w67, xs, a67);
        }
        float accv[8] = {a01.x, a01.y, a23.x, a23.y, a45.x, a45.y, a67.x, a67.y};
        __syncthreads();
#pragma unroll
        for (int k = 0; k < 8; ++k) T[k * 264 + t + (t >> 5)] = accv[k];
        __syncthreads();
#pragma unroll
        for (int e = 0; e < 8; ++e) {
            int flat = (e << 8) + t;
            int wcol = flat >> 6, oo = (flat >> 3) & 7, il = flat & 7;
            int mm = (il << 5) + wcol;
            qb[(size_t)wcol * 7168 + (o0 + oo) * 56 + il] = T[oo * 264 + mm + (mm >> 5)];
        }
        {
            int row = t >> 5, part = t & 31;
            float s1 = 0.f, s2 = 0.f;
#pragma unroll
            for (int e = 0; e < 8; ++e) {
                int mm = (part << 3) + e;
                float v = T[row * 264 + mm + (mm >> 5)];
                s1 += v; s2 += v * v;
            }
#pragma unroll
            for (int off = 16; off > 0; off >>= 1) {
                s1 += __shfl_xor(s1, off);
                s2 += __shfl_xor(s2, off);
            }
            if (part == 0) {
                P[(o0 + row) * 224 + tile] = s1;
                P[(128 + o0 + row) * 224 + tile] = s2;
            }
        }
    }
}

// =============== coalesced partial reduction -> BN params (256 threads) ===============
__global__ __launch_bounds__(256) void k_fin_red(const float* __restrict__ P,
                                                 const float* __restrict__ g,
                                                 const float* __restrict__ bb,
                                                 float* __restrict__ prm,
                                                 int nch, int npart, float invN) {
    __shared__ float rd[8];
    const int c = blockIdx.x, t = threadIdx.x;
    const float* r1 = P + (size_t)c * npart;
    const float* r2 = P + (size_t)(nch + c) * npart;
    float s1 = 0.f, s2 = 0.f;
    for (int p = t; p < npart; p += 256) { s1 += r1[p]; s2 += r2[p]; }
#pragma unroll
    for (int off = 32; off > 0; off >>= 1) { s1 += __shfl_xor(s1, off); s2 += __shfl_xor(s2, off); }
    if ((t & 63) == 0) { rd[t >> 6] = s1; rd[4 + (t >> 6)] = s2; }
    __syncthreads();
    if (t == 0) {
        s1 = rd[0] + rd[1] + rd[2] + rd[3];
        s2 = rd[4] + rd[5] + rd[6] + rd[7];
        float m = s1 * invN;
        float v = s2 * invN - m * m;
        float sc = g[c] * rsqrtf(v + EPS);
        prm[c] = sc;
        prm[nch + c] = bb[c] - m * sc;
    }
}

// =============== small finalize (fallback out BN) ===============
__global__ void k_fin(const float* __restrict__ sums, const float* __restrict__ g,
                      const float* __restrict__ bb, float* __restrict__ prm,
                      int nch, float invN) {
    int c = threadIdx.x;
    if (c >= nch) return;
    float m = sums[c] * invN;
    float v = sums[nch + c] * invN - m * m;
    float sc = g[c] * rsqrtf(v + EPS);
    prm[c] = sc;
    prm[nch + c] = bb[c] - m * sc;
}

// =============== K3: algebraic sim statistics (packed, stride 58) ===============
__global__ __launch_bounds__(256) void k_sim2(const float* __restrict__ qkv,
                                              const float* __restrict__ prmQ,
                                              const float* __restrict__ tab,
                                              float* __restrict__ P) {
    __shared__ float qn[64 * 58];
    __shared__ float T[40 * 58];
    __shared__ float red[8 * 6];
    const int t = threadIdx.x, b = blockIdx.x;

    const float* span = qkv + (size_t)b * 7168;
    for (int idx = t; idx < 3584; idx += 256) {
        int g = idx / 448, r = idx - g * 448, c = r / 56, i = r - c * 56;
        int ch = g * 16 + c;
        qn[(g * 8 + c) * 58 + i] = span[g * 896 + r] * prmQ[ch] + prmQ[128 + ch];
    }
    for (int idx = t; idx < 2240; idx += 256) {
        int row = idx / 56, i = idx - row * 56;
        int lr = (row < 8) ? (32 + row) : (row - 8);
        T[lr * 58 + i] = tab[idx];
    }
    __syncthreads();

    const int g = t >> 5, u = t & 31;
    const int half = (u < 16) ? 0 : 4;
    const float* rowA = &qn[g * 464 + (half + ((u >> 2) & 3)) * 58];
    const float* rowB = &qn[g * 464 + (half + (u & 3)) * 58];
    const float* tabS = &T[u * 58];
    const float* tabR = &T[(32 + half + (u & 3)) * 58];

    f32x2 gram2 = {0, 0}, wgt2 = {0, 0}, lin12 = {0, 0}, lin22 = {0, 0};
#pragma unroll
    for (int i = 0; i < 56; i += 2) {
        f32x2 a = *(const f32x2*)&rowA[i];
        f32x2 b2 = *(const f32x2*)&rowB[i];
        f32x2 p = a * b2;
        gram2 += p;
        wgt2 = fma2(p, *(const f32x2*)&tabS[i], wgt2);
        lin12 += b2;
        lin22 = fma2(b2, *(const f32x2*)&tabR[i], lin22);
    }
    float gram = gram2.x + gram2.y, wgt = wgt2.x + wgt2.y;
    float lin1 = lin12.x + lin12.y, lin2 = lin22.x + lin22.y;

    float linP = __shfl_xor(lin1, 16);
    float gramP = __shfl_xor(gram, 16);
    float v0 = (u < 4) ? lin1 * linP : 0.f;
    float v1 = (u < 16) ? gram * gramP : 0.f;
    float v2 = (u < 4) ? lin2 : 0.f;
    float v3 = (u < 16) ? wgt : 0.f;
    float v4 = (u >= 16 && u < 20) ? lin2 : 0.f;
    float v5 = (u >= 16) ? wgt : 0.f;
#pragma unroll
    for (int off = 16; off > 0; off >>= 1) {
        v0 += __shfl_xor(v0, off); v1 += __shfl_xor(v1, off);
        v2 += __shfl_xor(v2, off); v3 += __shfl_xor(v3, off);
        v4 += __shfl_xor(v4, off); v5 += __shfl_xor(v5, off);
    }
    if (u == 0) {
        red[g * 6 + 0] = v0; red[g * 6 + 1] = v1; red[g * 6 + 2] = v2;
        red[g * 6 + 3] = v3; red[g * 6 + 4] = v4; red[g * 6 + 5] = v5;
    }
    __syncthreads();
    if (t < 48) {
        int g2 = t / 6, s = t - g2 * 6;
        int row = ((s & 1) ? 24 : 0) + (s >> 1) * 8 + g2;
        P[(size_t)row * 1024 + b] = red[g2 * 6 + s];
    }
}

// =============== K5: fused QK/BN/exp -> PV, packed fp32 + b128 LDS ===============
__global__ __launch_bounds__(256) void k_main5(float* __restrict__ qkv,
                                               const float* __restrict__ rel,
                                               const float* __restrict__ prmQ,
                                               const float* __restrict__ prmS,
                                               float* __restrict__ P2,
                                               int useP2) {
    const int bg = blockIdx.x;
    const int g = bg & 7;
    __shared__ __align__(16) float S[16 * 60];    // q 0-3, k 4-7, v 8-15
    __shared__ __align__(16) float rall[1776];    // rq[4][111] rk[4][111] rvrev[8][111]
    __shared__ __align__(16) float Pm[56 * 60];   // raw exp values, 16B-aligned rows
    __shared__ float red[128];

    const int t = threadIdx.x;
    float* span = qkv + (size_t)bg * 896;

    // ---- stage: BN'd q/k/v into S rows ----
    if (t < 224) {
        int e0 = t * 4;
        int c = e0 / 56, i = e0 - c * 56;
        int ch = g * 16 + c;
        float sc = prmQ[ch], sh = prmQ[128 + ch];
        float4 vv = *(const float4*)&span[e0];
        float4 o;
        o.x = vv.x * sc + sh; o.y = vv.y * sc + sh;
        o.z = vv.z * sc + sh; o.w = vv.w * sc + sh;
        *(float4*)&S[c * 60 + i] = o;
    }
    // rq/rk flat; rv stored REVERSED so PV windows ascend
    for (int idx = t; idx < 222; idx += 256)
        *(float4*)&rall[idx * 4] = *(const float4*)&rel[idx * 4];
    for (int idx = t; idx < 888; idx += 256) {
        int c = idx / 111, u = idx - c * 111;
        rall[888 + c * 111 + u] = rel[888 + c * 111 + 110 - u];
    }
    __syncthreads();

    const int lane = t & 63, w = t >> 6;
    const int i_base = w * 14;
    const bool act = lane < 56;
    const int j = act ? lane : 0;

    const float k0 = S[240 + j], k1 = S[300 + j], k2 = S[360 + j], k3 = S[420 + j];
    const float sc_qk = prmS[g], sc_qr = prmS[8 + g], sc_kr = prmS[16 + g];
    const float sh_all = prmS[24 + g] + prmS[32 + g] + prmS[40 + g];

    // ---- scores (packed over row pairs) + exp, raw e -> Pm ----
    for (int r = 0; r < 14; r += 2) {
        const int i0 = i_base + r;                     // even -> aligned f32x2
        f32x2 q0 = *(const f32x2*)&S[i0];
        f32x2 q1 = *(const f32x2*)&S[60 + i0];
        f32x2 q2 = *(const f32x2*)&S[120 + i0];
        f32x2 q3 = *(const f32x2*)&S[180 + i0];
        const float* rq = &rall[i0 - j + 55];
        const float* rk = &rall[444 + j - i0 + 54];

        f32x2 qk = q0 * k0;
        qk = fma2(q1, sp2(k1), qk);
        qk = fma2(q2, sp2(k2), qk);
        qk = fma2(q3, sp2(k3), qk);

        f32x2 rq0 = {rq[0], rq[1]},     rq1 = {rq[111], rq[112]};
        f32x2 rq2 = {rq[222], rq[223]}, rq3 = {rq[333], rq[334]};
        f32x2 qr = q0 * rq0;
        qr = fma2(q1, rq1, qr);
        qr = fma2(q2, rq2, qr);
        qr = fma2(q3, rq3, qr);

        f32x2 rk0 = {rk[1], rk[0]},     rk1 = {rk[112], rk[111]};
        f32x2 rk2 = {rk[223], rk[222]}, rk3 = {rk[334], rk[333]};
        f32x2 kr = sp2(k0) * rk0;
        kr = fma2(sp2(k1), rk1, kr);
        kr = fma2(sp2(k2), rk2, kr);
        kr = fma2(sp2(k3), rk3, kr);

        f32x2 s = qk * sc_qk;
        s = fma2(qr, sp2(sc_qr), s);
        s = fma2(kr, sp2(sc_kr), s);
        s += sh_all;
        float e0 = act ? __expf(s.x) : 0.f;
        float e1 = act ? __expf(s.y) : 0.f;
        if (act) {
            Pm[i0 * 60 + j] = e0;
            Pm[(i0 + 1) * 60 + j] = e1;
        }
    }
    // no __syncthreads: each wave consumes only its own rows (DS pipe in-order)

    // ---- PV with inline rowsum; lane = 16-aligned (cc, il), f32x4 math ----
    const int il = lane & 15, cc = lane >> 4;
    const bool pact = il < 14;
    const int i = pact ? (i_base + il) : i_base;

#pragma unroll
    for (int pass = 0; pass < 2; ++pass) {
        const int c = cc + (pass << 2);
        const float* Pb = &Pm[i * 60];
        const float* vb = &S[(8 + c) * 60];
        const float* rvb = &rall[888 + c * 111 + 55 - i];   // ascending window
        f32x4 sv4 = {0, 0, 0, 0}, sve4 = {0, 0, 0, 0}, rs4 = {0, 0, 0, 0};
        for (int jj = 0; jj < 56; jj += 4) {
            f32x4 p4 = *(const f32x4*)&Pb[jj];
            f32x4 v4 = *(const f32x4*)&vb[jj];
            f32x4 r4 = {rvb[jj], rvb[jj + 1], rvb[jj + 2], rvb[jj + 3]};
            sv4 = fma4(p4, v4, sv4);
            sve4 = fma4(p4, r4, sve4);
            rs4 += p4;
        }
        float sv = (sv4.x + sv4.y) + (sv4.z + sv4.w);
        float sve = (sve4.x + sve4.y) + (sve4.z + sve4.w);
        float rs = (rs4.x + rs4.y) + (rs4.z + rs4.w);
        float inv = __builtin_amdgcn_rcpf(rs);
        sv *= inv; sve *= inv;
        if (pact) {
            span[(c * 2) * 56 + i] = sv;
            span[(c * 2 + 1) * 56 + i] = sve;
        }
        float a0 = pact ? sv : 0.f,  a1 = pact ? sv * sv : 0.f;
        float a2 = pact ? sve : 0.f, a3 = pact ? sve * sve : 0.f;
#pragma unroll
        for (int off = 8; off > 0; off >>= 1) {
            a0 += __shfl_xor(a0, off); a1 += __shfl_xor(a1, off);
            a2 += __shfl_xor(a2, off); a3 += __shfl_xor(a3, off);
        }
        if (il == 0) {
            int base = ((pass * 4 + cc) * 4) * 4 + w;
            red[base + 0]  = a0;
            red[base + 4]  = a1;
            red[base + 8]  = a2;
            red[base + 12] = a3;
        }
    }
    __syncthreads();
    if (useP2 && t < 32) {
        float s = red[t * 4] + red[t * 4 + 1] + red[t * 4 + 2] + red[t * 4 + 3];
        int pass = t >> 4, cc2 = (t >> 2) & 3, v = t & 3;
        int c = cc2 + (pass << 2);
        int ch = g * 16 + c * 2 + (v >> 1);
        int row = (v & 1) ? (128 + ch) : ch;
        P2[(size_t)row * 8192 + bg] = s;
    }
}

// =============== fallback out stats ===============
__global__ __launch_bounds__(256) void k_stats(const float* __restrict__ so,
                                               float* __restrict__ sums) {
    const int t = threadIdx.x;
    const int o = blockIdx.x >> 3;
    const int b0 = (blockIdx.x & 7) << 7;
    float s1 = 0.f, s2 = 0.f;
#pragma unroll
    for (int j = 0; j < 7; ++j) {
        int f = (j << 8) + t;
        int row = f / 14, q = f - row * 14;
        const float* src = so + ((size_t)(b0 + row) * 128 + o) * 56 + (q << 2);
        float4 v = *(const float4*)src;
        s1 += v.x + v.y + v.z + v.w;
        s2 += v.x * v.x + v.y * v.y + v.z * v.z + v.w * v.w;
    }
#pragma unroll
    for (int off = 32; off > 0; off >>= 1) { s1 += __shfl_xor(s1, off); s2 += __shfl_xor(s2, off); }
    if ((t & 63) == 0) { atomicAdd(&sums[o], s1); atomicAdd(&sums[128 + o], s2); }
}

// =============== K7: out BN + channel-pair sum + transpose ===============
__global__ __launch_bounds__(256) void k_out2(const float* __restrict__ so,
                                              const float* __restrict__ prmO,
                                              float* __restrict__ out) {
    __shared__ float L[128 * 61];
    const int t = threadIdx.x;
    const int s = blockIdx.x & 31;
    const int pc = blockIdx.x >> 5;
    const int o0 = pc << 2;
    const int p0 = pc << 1;

#pragma unroll
    for (int j = 0; j < 7; ++j) {
        int f = (j << 8) + t;
        int row = f / 14, q = f - row * 14;
        int ch = row >> 5, wcol = row & 31;
        const float* src = so + ((size_t)(s * 32 + wcol) * 128 + o0 + ch) * 56 + (q << 2);
        float4 v = *(const float4*)src;
        float* dst = &L[row * 61 + (q << 2)];
        dst[0] = v.x; dst[1] = v.y; dst[2] = v.z; dst[3] = v.w;
    }
    __syncthreads();
#pragma unroll
    for (int j = 0; j < 14; ++j) {
        int flat = (j << 8) + t;
        int wcol = flat & 31, r = flat >> 5;
        int i = r % 56, pp = r / 56;
        float v0 = L[((pp * 2) * 32 + wcol) * 61 + i];
        float v1 = L[((pp * 2 + 1) * 32 + wcol) * 61 + i];
        float sc0 = prmO[o0 + (pp << 1)],     sh0 = prmO[128 + o0 + (pp << 1)];
        float sc1 = prmO[o0 + (pp << 1) + 1], sh1 = prmO[128 + o0 + (pp << 1) + 1];
        out[(((size_t)(p0 + pp) * 32 + s) * 56 + i) * 32 + wcol] =
            v0 * sc0 + sh0 + v1 * sc1 + sh1;
    }
}

extern "C" void kernel_launch(void* const* d_in, const int* in_sizes, int n_in,
                              void* d_out, int out_size, void* d_ws, size_t ws_size,
                              hipStream_t stream) {
    const float* x     = (const float*)d_in[0];
    const float* w_qkv = (const float*)d_in[1];
    const float* g_qkv = (const float*)d_in[2];
    const float* b_qkv = (const float*)d_in[3];
    const float* g_sim = (const float*)d_in[4];
    const float* b_sim = (const float*)d_in[5];
    const float* g_out = (const float*)d_in[6];
    const float* b_out = (const float*)d_in[7];
    const float* rel   = (const float*)d_in[8];
    float* out = (float*)d_out;

    float* ws    = (float*)d_ws;
    float* qkv   = ws;
    float* Pq    = ws + 7340032;
    float* prm   = ws + 7397376;
    float* tab   = ws + 7397936;
    float* sumsO = ws + 7400176;
    float* P2    = ws + 7400448;
    const bool big = ws_size >= (size_t)(7400448 + 2097152) * sizeof(float);

    k_qkv2<<<449, 256, 0, stream>>>(x, w_qkv, rel, qkv, Pq, tab);
    k_fin_red<<<128, 256, 0, stream>>>(Pq, g_qkv, b_qkv, prm, 128, 224, 1.f / 57344.f);
    k_sim2<<<1024, 256, 0, stream>>>(qkv, prm, tab, Pq);
    k_fin_red<<<24, 256, 0, stream>>>(Pq, g_sim, b_sim, prm + 256, 24, 1024, 1.f / 3211264.f);

    if (big) {
        k_main5<<<8192, 256, 0, stream>>>(qkv, rel, prm, prm + 256, P2, 1);
        k_fin_red<<<128, 256, 0, stream>>>(P2, g_out, b_out, prm + 304, 128, 8192, 1.f / 57344.f);
    } else {
        hipMemsetAsync(sumsO, 0, 256 * sizeof(float), stream);
        k_main5<<<8192, 256, 0, stream>>>(qkv, rel, prm, prm + 256, sumsO, 0);
        k_stats<<<1024, 256, 0, stream>>>(qkv, sumsO);
        k_fin<<<1, 128, 0, stream>>>(sumsO, g_out, b_out, prm + 304, 128, 1.f / 57344.f);
    }
    k_out2<<<1024, 256, 0, stream>>>(qkv, prm + 304, out);
}

// Round 7
// 130.456 us; speedup vs baseline: 2.3521x; 1.1031x over previous
//
#include <hip/hip_runtime.h>
#include <math.h>

#define EPS 1e-5f

typedef float f32x2 __attribute__((ext_vector_type(2)));
typedef float f32x4 __attribute__((ext_vector_type(4)));
__device__ __forceinline__ f32x2 fma2(f32x2 a, f32x2 b, f32x2 c) {
    return __builtin_elementwise_fma(a, b, c);
}
__device__ __forceinline__ f32x4 fma4(f32x4 a, f32x4 b, f32x4 c) {
    return __builtin_elementwise_fma(a, b, c);
}
__device__ __forceinline__ f32x2 sp2(float x) { f32x2 r = {x, x}; return r; }

// ---------------- workspace layout (floats) ----------------
// qkv   : 0          [7,340,032]  qkv, overwritten in-place with "so"
// Pq    : +7340032   [57,344]     partials: qkv [256][224], reused as sim [48][1024]
// prm   : +7397376   [560]        qkvP[256] | simP[48] | outP[256]
// tab   : +7397936   [3,128]      Rq/Rk/Sq/Sk window sums [2240] + rvrev [888]
// sumsO : +7401064   [256]        fallback out stats
// P2    : +7401472   [262,144]    out partials [256][1024]

// =============== K1: tiled GEMM (packed fp32) + transpose-write + stats;
//                 block 448 computes window-sum tables + reversed rv ===============
__global__ __launch_bounds__(256) void k_qkv2(const float* __restrict__ x,
                                              const float* __restrict__ w,
                                              const float* __restrict__ rel,
                                              float* __restrict__ qkv,
                                              float* __restrict__ P,
                                              float* __restrict__ tab) {
    __shared__ __align__(16) float X[64 * 256];
    __shared__ float T[8 * 264];
    const int t = threadIdx.x;

    if (blockIdx.x == 448) {            // ---- prep path ----
        float* r = X;
        for (int idx = t; idx < 1776; idx += 256) r[idx] = rel[idx];
        __syncthreads();
        for (int o = t; o < 2240; o += 256) {
            int row = o / 56, i = o - row * 56;
            float s = 0.f;
            if (row < 8) {
                const float* rr = &r[row * 111];
#pragma unroll
                for (int u = 0; u < 56; ++u) s += rr[i + u];
            } else if (row < 24) {
                int p = row - 8;
                const float* ra = &r[(p >> 2) * 111];
                const float* rb = &r[(p & 3) * 111];
#pragma unroll
                for (int u = 0; u < 56; ++u) s = fmaf(ra[i + u], rb[i + u], s);
            } else {
                int p = row - 24;
                const float* ra = &r[(4 + (p >> 2)) * 111];
                const float* rb = &r[(4 + (p & 3)) * 111];
#pragma unroll
                for (int u = 0; u < 56; ++u) s = fmaf(ra[i + u], rb[i + u], s);
            }
            tab[o] = s;
        }
        // reversed v-embedding rows so k_main can stage with f32x4
        for (int o = t; o < 888; o += 256) {
            int c = o / 111, u = o - c * 111;
            tab[2240 + o] = rel[888 + c * 111 + 110 - u];
        }
        return;
    }

    const int tile = blockIdx.x % 224;
    const int half = blockIdx.x / 224;
    const int m0 = tile << 8;
    const int s = m0 / 1792;
    const int i0 = (m0 - s * 1792) >> 5;

    const float* xb = x + m0;
#pragma unroll
    for (int j = 0; j < 16; ++j) {
        int f = (j << 8) + t;
        int c = f >> 6, col = (f & 63) << 2;
        *(float4*)&X[(c << 8) + col] = *(const float4*)&xb[(size_t)c * 57344 + col];
    }
    __syncthreads();

    float* qb = qkv + (size_t)s * 229376 + i0;

    for (int oc = half * 8; oc < half * 8 + 8; ++oc) {
        const int o0 = oc << 3;
        const float* wp = w + (o0 << 6);
        f32x2 a01 = {0, 0}, a23 = {0, 0}, a45 = {0, 0}, a67 = {0, 0};
        for (int c = 0; c < 64; ++c) {
            float xv = X[(c << 8) + t];
            f32x2 w01 = {wp[c], wp[64 + c]};
            f32x2 w23 = {wp[128 + c], wp[192 + c]};
            f32x2 w45 = {wp[256 + c], wp[320 + c]};
            f32x2 w67 = {wp[384 + c], wp[448 + c]};
            f32x2 xs = sp2(xv);
            a01 = fma2(w01, xs, a01);
            a23 = fma2(w23, xs, a23);
            a45 = fma2(w45, xs, a45);
            a67 = fma2(w67, xs, a67);
        }
        float accv[8] = {a01.x, a01.y, a23.x, a23.y, a45.x, a45.y, a67.x, a67.y};
        __syncthreads();
#pragma unroll
        for (int k = 0; k < 8; ++k) T[k * 264 + t + (t >> 5)] = accv[k];
        __syncthreads();
#pragma unroll
        for (int e = 0; e < 8; ++e) {
            int flat = (e << 8) + t;
            int wcol = flat >> 6, oo = (flat >> 3) & 7, il = flat & 7;
            int mm = (il << 5) + wcol;
            qb[(size_t)wcol * 7168 + (o0 + oo) * 56 + il] = T[oo * 264 + mm + (mm >> 5)];
        }
        {
            int row = t >> 5, part = t & 31;
            float s1 = 0.f, s2 = 0.f;
#pragma unroll
            for (int e = 0; e < 8; ++e) {
                int mm = (part << 3) + e;
                float v = T[row * 264 + mm + (mm >> 5)];
                s1 += v; s2 += v * v;
            }
#pragma unroll
            for (int off = 16; off > 0; off >>= 1) {
                s1 += __shfl_xor(s1, off);
                s2 += __shfl_xor(s2, off);
            }
            if (part == 0) {
                P[(o0 + row) * 224 + tile] = s1;
                P[(128 + o0 + row) * 224 + tile] = s2;
            }
        }
    }
}

// =============== coalesced partial reduction -> BN params ===============
__global__ __launch_bounds__(256) void k_fin_red(const float* __restrict__ P,
                                                 const float* __restrict__ g,
                                                 const float* __restrict__ bb,
                                                 float* __restrict__ prm,
                                                 int nch, int npart, float invN) {
    __shared__ float rd[8];
    const int c = blockIdx.x, t = threadIdx.x;
    const float* r1 = P + (size_t)c * npart;
    const float* r2 = P + (size_t)(nch + c) * npart;
    float s1 = 0.f, s2 = 0.f;
    for (int p = t; p < npart; p += 256) { s1 += r1[p]; s2 += r2[p]; }
#pragma unroll
    for (int off = 32; off > 0; off >>= 1) { s1 += __shfl_xor(s1, off); s2 += __shfl_xor(s2, off); }
    if ((t & 63) == 0) { rd[t >> 6] = s1; rd[4 + (t >> 6)] = s2; }
    __syncthreads();
    if (t == 0) {
        s1 = rd[0] + rd[1] + rd[2] + rd[3];
        s2 = rd[4] + rd[5] + rd[6] + rd[7];
        float m = s1 * invN;
        float v = s2 * invN - m * m;
        float sc = g[c] * rsqrtf(v + EPS);
        prm[c] = sc;
        prm[nch + c] = bb[c] - m * sc;
    }
}

// =============== small finalize (fallback out BN) ===============
__global__ void k_fin(const float* __restrict__ sums, const float* __restrict__ g,
                      const float* __restrict__ bb, float* __restrict__ prm,
                      int nch, float invN) {
    int c = threadIdx.x;
    if (c >= nch) return;
    float m = sums[c] * invN;
    float v = sums[nch + c] * invN - m * m;
    float sc = g[c] * rsqrtf(v + EPS);
    prm[c] = sc;
    prm[nch + c] = bb[c] - m * sc;
}

// =============== K3: algebraic sim statistics (packed, stride 58) ===============
__global__ __launch_bounds__(256) void k_sim2(const float* __restrict__ qkv,
                                              const float* __restrict__ prmQ,
                                              const float* __restrict__ tab,
                                              float* __restrict__ P) {
    __shared__ float qn[64 * 58];
    __shared__ float T[40 * 58];
    __shared__ float red[8 * 6];
    const int t = threadIdx.x, b = blockIdx.x;

    const float* span = qkv + (size_t)b * 7168;
    for (int idx = t; idx < 3584; idx += 256) {
        int g = idx / 448, r = idx - g * 448, c = r / 56, i = r - c * 56;
        int ch = g * 16 + c;
        qn[(g * 8 + c) * 58 + i] = span[g * 896 + r] * prmQ[ch] + prmQ[128 + ch];
    }
    for (int idx = t; idx < 2240; idx += 256) {
        int row = idx / 56, i = idx - row * 56;
        int lr = (row < 8) ? (32 + row) : (row - 8);
        T[lr * 58 + i] = tab[idx];
    }
    __syncthreads();

    const int g = t >> 5, u = t & 31;
    const int half = (u < 16) ? 0 : 4;
    const float* rowA = &qn[g * 464 + (half + ((u >> 2) & 3)) * 58];
    const float* rowB = &qn[g * 464 + (half + (u & 3)) * 58];
    const float* tabS = &T[u * 58];
    const float* tabR = &T[(32 + half + (u & 3)) * 58];

    f32x2 gram2 = {0, 0}, wgt2 = {0, 0}, lin12 = {0, 0}, lin22 = {0, 0};
#pragma unroll
    for (int i = 0; i < 56; i += 2) {
        f32x2 a = *(const f32x2*)&rowA[i];
        f32x2 b2 = *(const f32x2*)&rowB[i];
        f32x2 p = a * b2;
        gram2 += p;
        wgt2 = fma2(p, *(const f32x2*)&tabS[i], wgt2);
        lin12 += b2;
        lin22 = fma2(b2, *(const f32x2*)&tabR[i], lin22);
    }
    float gram = gram2.x + gram2.y, wgt = wgt2.x + wgt2.y;
    float lin1 = lin12.x + lin12.y, lin2 = lin22.x + lin22.y;

    float linP = __shfl_xor(lin1, 16);
    float gramP = __shfl_xor(gram, 16);
    float v0 = (u < 4) ? lin1 * linP : 0.f;
    float v1 = (u < 16) ? gram * gramP : 0.f;
    float v2 = (u < 4) ? lin2 : 0.f;
    float v3 = (u < 16) ? wgt : 0.f;
    float v4 = (u >= 16 && u < 20) ? lin2 : 0.f;
    float v5 = (u >= 16) ? wgt : 0.f;
#pragma unroll
    for (int off = 16; off > 0; off >>= 1) {
        v0 += __shfl_xor(v0, off); v1 += __shfl_xor(v1, off);
        v2 += __shfl_xor(v2, off); v3 += __shfl_xor(v3, off);
        v4 += __shfl_xor(v4, off); v5 += __shfl_xor(v5, off);
    }
    if (u == 0) {
        red[g * 6 + 0] = v0; red[g * 6 + 1] = v1; red[g * 6 + 2] = v2;
        red[g * 6 + 3] = v3; red[g * 6 + 4] = v4; red[g * 6 + 5] = v5;
    }
    __syncthreads();
    if (t < 48) {
        int g2 = t / 6, s = t - g2 * 6;
        int row = ((s & 1) ? 24 : 0) + (s >> 1) * 8 + g2;
        P[(size_t)row * 1024 + b] = red[g2 * 6 + s];
    }
}

// =============== K5: fused QK/BN/exp -> single-pass dual-channel PV ===============
__global__ __launch_bounds__(256) void k_main6(float* __restrict__ qkv,
                                               const float* __restrict__ rel,
                                               const float* __restrict__ tabrv,
                                               const float* __restrict__ prmQ,
                                               const float* __restrict__ prmS,
                                               float* __restrict__ P2,
                                               int useP2) {
    const int bg = blockIdx.x;
    const int g = bg & 7;
    __shared__ __align__(16) float S[16 * 60];    // q 0-3, k 4-7, v 8-15
    __shared__ __align__(16) float rall[1776];    // rq[4][111] rk[4][111] rvrev[8][111]
    __shared__ __align__(16) float Pm[56 * 60];   // raw exp values
    __shared__ float red[128];

    const int t = threadIdx.x;
    float* span = qkv + (size_t)bg * 896;

    // ---- stage: BN'd q/k/v into S; rq/rk from rel, rvrev from tab (all f32x4) ----
    if (t < 224) {
        int e0 = t * 4;
        int c = e0 / 56, i = e0 - c * 56;
        int ch = g * 16 + c;
        float sc = prmQ[ch], sh = prmQ[128 + ch];
        float4 vv = *(const float4*)&span[e0];
        float4 o;
        o.x = vv.x * sc + sh; o.y = vv.y * sc + sh;
        o.z = vv.z * sc + sh; o.w = vv.w * sc + sh;
        *(float4*)&S[c * 60 + i] = o;
    }
    for (int idx = t; idx < 222; idx += 256)
        *(float4*)&rall[idx * 4] = *(const float4*)&rel[idx * 4];
    for (int idx = t; idx < 222; idx += 256)
        *(float4*)&rall[888 + idx * 4] = *(const float4*)&tabrv[idx * 4];
    __syncthreads();

    const int lane = t & 63, w = t >> 6;
    const int i_base = w * 14;
    const bool act = lane < 56;
    const int j = act ? lane : 0;

    const float k0 = S[240 + j], k1 = S[300 + j], k2 = S[360 + j], k3 = S[420 + j];
    const float sc_qk = prmS[g], sc_qr = prmS[8 + g], sc_kr = prmS[16 + g];
    const float sh_all = prmS[24 + g] + prmS[32 + g] + prmS[40 + g];

    // ---- scores (packed row pairs) + exp, raw e -> Pm ----
#pragma unroll 2
    for (int r = 0; r < 14; r += 2) {
        const int i0 = i_base + r;
        f32x2 q0 = *(const f32x2*)&S[i0];
        f32x2 q1 = *(const f32x2*)&S[60 + i0];
        f32x2 q2 = *(const f32x2*)&S[120 + i0];
        f32x2 q3 = *(const f32x2*)&S[180 + i0];
        const float* rq = &rall[i0 - j + 55];
        const float* rk = &rall[444 + j - i0 + 54];

        f32x2 qk = q0 * k0;
        qk = fma2(q1, sp2(k1), qk);
        qk = fma2(q2, sp2(k2), qk);
        qk = fma2(q3, sp2(k3), qk);

        f32x2 rq0 = {rq[0], rq[1]},     rq1 = {rq[111], rq[112]};
        f32x2 rq2 = {rq[222], rq[223]}, rq3 = {rq[333], rq[334]};
        f32x2 qr = q0 * rq0;
        qr = fma2(q1, rq1, qr);
        qr = fma2(q2, rq2, qr);
        qr = fma2(q3, rq3, qr);

        f32x2 rk0 = {rk[1], rk[0]},     rk1 = {rk[112], rk[111]};
        f32x2 rk2 = {rk[223], rk[222]}, rk3 = {rk[334], rk[333]};
        f32x2 kr = sp2(k0) * rk0;
        kr = fma2(sp2(k1), rk1, kr);
        kr = fma2(sp2(k2), rk2, kr);
        kr = fma2(sp2(k3), rk3, kr);

        f32x2 s = qk * sc_qk;
        s = fma2(qr, sp2(sc_qr), s);
        s = fma2(kr, sp2(sc_kr), s);
        s += sh_all;
        float e0 = act ? __expf(s.x) : 0.f;
        float e1 = act ? __expf(s.y) : 0.f;
        if (act) {
            Pm[i0 * 60 + j] = e0;
            Pm[(i0 + 1) * 60 + j] = e1;
        }
    }
    // no __syncthreads: each wave consumes only its own rows (DS pipe in-order)

    // ---- single-pass PV: group (cc) handles channels cc and cc+4 ----
    const int il = lane & 15, cc = lane >> 4;
    const bool pact = il < 14;
    const int i = pact ? (i_base + il) : i_base;
    const int cA = cc, cB = cc + 4;

    const float* Pb  = &Pm[i * 60];
    const float* vbA = &S[(8 + cA) * 60];
    const float* vbB = &S[(8 + cB) * 60];
    const float* rvA = &rall[888 + cA * 111 + 55 - i];
    const float* rvB = &rall[888 + cB * 111 + 55 - i];
    f32x4 svA = {0, 0, 0, 0}, sveA = {0, 0, 0, 0};
    f32x4 svB = {0, 0, 0, 0}, sveB = {0, 0, 0, 0};
    f32x4 rs4 = {0, 0, 0, 0};
    for (int jj = 0; jj < 56; jj += 4) {
        f32x4 p4 = *(const f32x4*)&Pb[jj];
        f32x4 vA = *(const f32x4*)&vbA[jj];
        f32x4 vB = *(const f32x4*)&vbB[jj];
        f32x4 rA = {rvA[jj], rvA[jj + 1], rvA[jj + 2], rvA[jj + 3]};
        f32x4 rB = {rvB[jj], rvB[jj + 1], rvB[jj + 2], rvB[jj + 3]};
        svA = fma4(p4, vA, svA);  sveA = fma4(p4, rA, sveA);
        svB = fma4(p4, vB, svB);  sveB = fma4(p4, rB, sveB);
        rs4 += p4;
    }
    float rs = (rs4.x + rs4.y) + (rs4.z + rs4.w);
    float inv = __builtin_amdgcn_rcpf(rs);
    float sva = ((svA.x + svA.y) + (svA.z + svA.w)) * inv;
    float svea = ((sveA.x + sveA.y) + (sveA.z + sveA.w)) * inv;
    float svb = ((svB.x + svB.y) + (svB.z + svB.w)) * inv;
    float sveb = ((sveB.x + sveB.y) + (sveB.z + sveB.w)) * inv;
    if (pact) {
        span[(cA * 2) * 56 + i] = sva;
        span[(cA * 2 + 1) * 56 + i] = svea;
        span[(cB * 2) * 56 + i] = svb;
        span[(cB * 2 + 1) * 56 + i] = sveb;
    }
    // stats: 8 chains, 4-step shuffle within 16-lane groups
    float a0 = pact ? sva : 0.f,  a1 = pact ? sva * sva : 0.f;
    float a2 = pact ? svea : 0.f, a3 = pact ? svea * svea : 0.f;
    float a4 = pact ? svb : 0.f,  a5 = pact ? svb * svb : 0.f;
    float a6 = pact ? sveb : 0.f, a7 = pact ? sveb * sveb : 0.f;
#pragma unroll
    for (int off = 8; off > 0; off >>= 1) {
        a0 += __shfl_xor(a0, off); a1 += __shfl_xor(a1, off);
        a2 += __shfl_xor(a2, off); a3 += __shfl_xor(a3, off);
        a4 += __shfl_xor(a4, off); a5 += __shfl_xor(a5, off);
        a6 += __shfl_xor(a6, off); a7 += __shfl_xor(a7, off);
    }
    if (il == 0) {
        int baseA = cc * 16 + w;          // pass 0
        int baseB = (4 + cc) * 16 + w;    // pass 1
        red[baseA + 0]  = a0;  red[baseA + 4]  = a1;
        red[baseA + 8]  = a2;  red[baseA + 12] = a3;
        red[baseB + 0]  = a4;  red[baseB + 4]  = a5;
        red[baseB + 8]  = a6;  red[baseB + 12] = a7;
    }
    __syncthreads();
    if (useP2 && t < 32) {
        float s = red[t * 4] + red[t * 4 + 1] + red[t * 4 + 2] + red[t * 4 + 3];
        int pass = t >> 4, cc2 = (t >> 2) & 3, v = t & 3;
        int c = cc2 + (pass << 2);
        int ch = g * 16 + c * 2 + (v >> 1);
        int row = (v & 1) ? (128 + ch) : ch;
        P2[(size_t)row * 1024 + (bg >> 3)] = s;
    }
}

// =============== fallback out stats ===============
__global__ __launch_bounds__(256) void k_stats(const float* __restrict__ so,
                                               float* __restrict__ sums) {
    const int t = threadIdx.x;
    const int o = blockIdx.x >> 3;
    const int b0 = (blockIdx.x & 7) << 7;
    float s1 = 0.f, s2 = 0.f;
#pragma unroll
    for (int j = 0; j < 7; ++j) {
        int f = (j << 8) + t;
        int row = f / 14, q = f - row * 14;
        const float* src = so + ((size_t)(b0 + row) * 128 + o) * 56 + (q << 2);
        float4 v = *(const float4*)src;
        s1 += v.x + v.y + v.z + v.w;
        s2 += v.x * v.x + v.y * v.y + v.z * v.z + v.w * v.w;
    }
#pragma unroll
    for (int off = 32; off > 0; off >>= 1) { s1 += __shfl_xor(s1, off); s2 += __shfl_xor(s2, off); }
    if ((t & 63) == 0) { atomicAdd(&sums[o], s1); atomicAdd(&sums[128 + o], s2); }
}

// =============== K7: out BN + channel-pair sum + transpose ===============
__global__ __launch_bounds__(256) void k_out2(const float* __restrict__ so,
                                              const float* __restrict__ prmO,
                                              float* __restrict__ out) {
    __shared__ float L[128 * 61];
    const int t = threadIdx.x;
    const int s = blockIdx.x & 31;
    const int pc = blockIdx.x >> 5;
    const int o0 = pc << 2;
    const int p0 = pc << 1;

#pragma unroll
    for (int j = 0; j < 7; ++j) {
        int f = (j << 8) + t;
        int row = f / 14, q = f - row * 14;
        int ch = row >> 5, wcol = row & 31;
        const float* src = so + ((size_t)(s * 32 + wcol) * 128 + o0 + ch) * 56 + (q << 2);
        float4 v = *(const float4*)src;
        float* dst = &L[row * 61 + (q << 2)];
        dst[0] = v.x; dst[1] = v.y; dst[2] = v.z; dst[3] = v.w;
    }
    __syncthreads();
#pragma unroll
    for (int j = 0; j < 14; ++j) {
        int flat = (j << 8) + t;
        int wcol = flat & 31, r = flat >> 5;
        int i = r % 56, pp = r / 56;
        float v0 = L[((pp * 2) * 32 + wcol) * 61 + i];
        float v1 = L[((pp * 2 + 1) * 32 + wcol) * 61 + i];
        float sc0 = prmO[o0 + (pp << 1)],     sh0 = prmO[128 + o0 + (pp << 1)];
        float sc1 = prmO[o0 + (pp << 1) + 1], sh1 = prmO[128 + o0 + (pp << 1) + 1];
        out[(((size_t)(p0 + pp) * 32 + s) * 56 + i) * 32 + wcol] =
            v0 * sc0 + sh0 + v1 * sc1 + sh1;
    }
}

extern "C" void kernel_launch(void* const* d_in, const int* in_sizes, int n_in,
                              void* d_out, int out_size, void* d_ws, size_t ws_size,
                              hipStream_t stream) {
    const float* x     = (const float*)d_in[0];
    const float* w_qkv = (const float*)d_in[1];
    const float* g_qkv = (const float*)d_in[2];
    const float* b_qkv = (const float*)d_in[3];
    const float* g_sim = (const float*)d_in[4];
    const float* b_sim = (const float*)d_in[5];
    const float* g_out = (const float*)d_in[6];
    const float* b_out = (const float*)d_in[7];
    const float* rel   = (const float*)d_in[8];
    float* out = (float*)d_out;

    float* ws    = (float*)d_ws;
    float* qkv   = ws;
    float* Pq    = ws + 7340032;
    float* prm   = ws + 7397376;
    float* tab   = ws + 7397936;
    float* sumsO = ws + 7401064;
    float* P2    = ws + 7401472;
    const bool big = ws_size >= (size_t)(7401472 + 262144) * sizeof(float);

    k_qkv2<<<449, 256, 0, stream>>>(x, w_qkv, rel, qkv, Pq, tab);
    k_fin_red<<<128, 256, 0, stream>>>(Pq, g_qkv, b_qkv, prm, 128, 224, 1.f / 57344.f);
    k_sim2<<<1024, 256, 0, stream>>>(qkv, prm, tab, Pq);
    k_fin_red<<<24, 256, 0, stream>>>(Pq, g_sim, b_sim, prm + 256, 24, 1024, 1.f / 3211264.f);

    if (big) {
        k_main6<<<8192, 256, 0, stream>>>(qkv, rel, tab + 2240, prm, prm + 256, P2, 1);
        k_fin_red<<<128, 256, 0, stream>>>(P2, g_out, b_out, prm + 304, 128, 1024, 1.f / 57344.f);
    } else {
        hipMemsetAsync(sumsO, 0, 256 * sizeof(float), stream);
        k_main6<<<8192, 256, 0, stream>>>(qkv, rel, tab + 2240, prm, prm + 256, sumsO, 0);
        k_stats<<<1024, 256, 0, stream>>>(qkv, sumsO);
        k_fin<<<1, 128, 0, stream>>>(sumsO, g_out, b_out, prm + 304, 128, 1.f / 57344.f);
    }
    k_out2<<<1024, 256, 0, stream>>>(qkv, prm + 304, out);
}

// Round 8
// 129.633 us; speedup vs baseline: 2.3670x; 1.0064x over previous
//
#include <hip/hip_runtime.h>
#include <math.h>

#define EPS 1e-5f

typedef float f32x2 __attribute__((ext_vector_type(2)));
typedef float f32x4 __attribute__((ext_vector_type(4)));
__device__ __forceinline__ f32x2 fma2(f32x2 a, f32x2 b, f32x2 c) {
    return __builtin_elementwise_fma(a, b, c);
}
__device__ __forceinline__ f32x4 fma4(f32x4 a, f32x4 b, f32x4 c) {
    return __builtin_elementwise_fma(a, b, c);
}
__device__ __forceinline__ f32x2 sp2(float x) { f32x2 r = {x, x}; return r; }

// ---------------- workspace layout (floats) ----------------
// qkv   : 0          [7,340,032]  qkv, overwritten in-place with "so"
// Pq    : +7340032   [57,344]     partials: qkv [256][224], reused as sim [48][1024]
// prm   : +7397376   [560]        qkvP[256] | simP[48] | outP[256]
// tab   : +7397936   [3,128]      Rq/Rk/Sq/Sk window sums [2240] + rvrev [888]
// sumsO : +7401064   [256]        fallback out stats
// P2    : +7401472   [262,144]    out partials [256][1024]

// =============== K1: tiled GEMM (packed fp32) + transpose-write + stats;
//                 block 448 computes window-sum tables + reversed rv ===============
__global__ __launch_bounds__(256) void k_qkv2(const float* __restrict__ x,
                                              const float* __restrict__ w,
                                              const float* __restrict__ rel,
                                              float* __restrict__ qkv,
                                              float* __restrict__ P,
                                              float* __restrict__ tab) {
    __shared__ __align__(16) float X[64 * 256];
    __shared__ float T[8 * 264];
    const int t = threadIdx.x;

    if (blockIdx.x == 448) {            // ---- prep path ----
        float* r = X;
        for (int idx = t; idx < 1776; idx += 256) r[idx] = rel[idx];
        __syncthreads();
        for (int o = t; o < 2240; o += 256) {
            int row = o / 56, i = o - row * 56;
            float s = 0.f;
            if (row < 8) {
                const float* rr = &r[row * 111];
#pragma unroll
                for (int u = 0; u < 56; ++u) s += rr[i + u];
            } else if (row < 24) {
                int p = row - 8;
                const float* ra = &r[(p >> 2) * 111];
                const float* rb = &r[(p & 3) * 111];
#pragma unroll
                for (int u = 0; u < 56; ++u) s = fmaf(ra[i + u], rb[i + u], s);
            } else {
                int p = row - 24;
                const float* ra = &r[(4 + (p >> 2)) * 111];
                const float* rb = &r[(4 + (p & 3)) * 111];
#pragma unroll
                for (int u = 0; u < 56; ++u) s = fmaf(ra[i + u], rb[i + u], s);
            }
            tab[o] = s;
        }
        // reversed v-embedding rows so k_main can stage with f32x4
        for (int o = t; o < 888; o += 256) {
            int c = o / 111, u = o - c * 111;
            tab[2240 + o] = rel[888 + c * 111 + 110 - u];
        }
        return;
    }

    const int tile = blockIdx.x % 224;
    const int half = blockIdx.x / 224;
    const int m0 = tile << 8;
    const int s = m0 / 1792;
    const int i0 = (m0 - s * 1792) >> 5;

    const float* xb = x + m0;
#pragma unroll
    for (int j = 0; j < 16; ++j) {
        int f = (j << 8) + t;
        int c = f >> 6, col = (f & 63) << 2;
        *(float4*)&X[(c << 8) + col] = *(const float4*)&xb[(size_t)c * 57344 + col];
    }
    __syncthreads();

    float* qb = qkv + (size_t)s * 229376 + i0;

    for (int oc = half * 8; oc < half * 8 + 8; ++oc) {
        const int o0 = oc << 3;
        const float* wp = w + (o0 << 6);
        f32x2 a01 = {0, 0}, a23 = {0, 0}, a45 = {0, 0}, a67 = {0, 0};
        for (int c = 0; c < 64; ++c) {
            float xv = X[(c << 8) + t];
            f32x2 w01 = {wp[c], wp[64 + c]};
            f32x2 w23 = {wp[128 + c], wp[192 + c]};
            f32x2 w45 = {wp[256 + c], wp[320 + c]};
            f32x2 w67 = {wp[384 + c], wp[448 + c]};
            f32x2 xs = sp2(xv);
            a01 = fma2(w01, xs, a01);
            a23 = fma2(w23, xs, a23);
            a45 = fma2(w45, xs, a45);
            a67 = fma2(w67, xs, a67);
        }
        float accv[8] = {a01.x, a01.y, a23.x, a23.y, a45.x, a45.y, a67.x, a67.y};
        __syncthreads();
#pragma unroll
        for (int k = 0; k < 8; ++k) T[k * 264 + t + (t >> 5)] = accv[k];
        __syncthreads();
#pragma unroll
        for (int e = 0; e < 8; ++e) {
            int flat = (e << 8) + t;
            int wcol = flat >> 6, oo = (flat >> 3) & 7, il = flat & 7;
            int mm = (il << 5) + wcol;
            qb[(size_t)wcol * 7168 + (o0 + oo) * 56 + il] = T[oo * 264 + mm + (mm >> 5)];
        }
        {
            int row = t >> 5, part = t & 31;
            float s1 = 0.f, s2 = 0.f;
#pragma unroll
            for (int e = 0; e < 8; ++e) {
                int mm = (part << 3) + e;
                float v = T[row * 264 + mm + (mm >> 5)];
                s1 += v; s2 += v * v;
            }
#pragma unroll
            for (int off = 16; off > 0; off >>= 1) {
                s1 += __shfl_xor(s1, off);
                s2 += __shfl_xor(s2, off);
            }
            if (part == 0) {
                P[(o0 + row) * 224 + tile] = s1;
                P[(128 + o0 + row) * 224 + tile] = s2;
            }
        }
    }
}

// =============== coalesced partial reduction -> BN params ===============
__global__ __launch_bounds__(256) void k_fin_red(const float* __restrict__ P,
                                                 const float* __restrict__ g,
                                                 const float* __restrict__ bb,
                                                 float* __restrict__ prm,
                                                 int nch, int npart, float invN) {
    __shared__ float rd[8];
    const int c = blockIdx.x, t = threadIdx.x;
    const float* r1 = P + (size_t)c * npart;
    const float* r2 = P + (size_t)(nch + c) * npart;
    float s1 = 0.f, s2 = 0.f;
    for (int p = t; p < npart; p += 256) { s1 += r1[p]; s2 += r2[p]; }
#pragma unroll
    for (int off = 32; off > 0; off >>= 1) { s1 += __shfl_xor(s1, off); s2 += __shfl_xor(s2, off); }
    if ((t & 63) == 0) { rd[t >> 6] = s1; rd[4 + (t >> 6)] = s2; }
    __syncthreads();
    if (t == 0) {
        s1 = rd[0] + rd[1] + rd[2] + rd[3];
        s2 = rd[4] + rd[5] + rd[6] + rd[7];
        float m = s1 * invN;
        float v = s2 * invN - m * m;
        float sc = g[c] * rsqrtf(v + EPS);
        prm[c] = sc;
        prm[nch + c] = bb[c] - m * sc;
    }
}

// =============== small finalize (fallback out BN) ===============
__global__ void k_fin(const float* __restrict__ sums, const float* __restrict__ g,
                      const float* __restrict__ bb, float* __restrict__ prm,
                      int nch, float invN) {
    int c = threadIdx.x;
    if (c >= nch) return;
    float m = sums[c] * invN;
    float v = sums[nch + c] * invN - m * m;
    float sc = g[c] * rsqrtf(v + EPS);
    prm[c] = sc;
    prm[nch + c] = bb[c] - m * sc;
}

// =============== K3: algebraic sim statistics (packed, stride 58) ===============
__global__ __launch_bounds__(256) void k_sim2(const float* __restrict__ qkv,
                                              const float* __restrict__ prmQ,
                                              const float* __restrict__ tab,
                                              float* __restrict__ P) {
    __shared__ float qn[64 * 58];
    __shared__ float T[40 * 58];
    __shared__ float red[8 * 6];
    const int t = threadIdx.x, b = blockIdx.x;

    const float* span = qkv + (size_t)b * 7168;
    for (int idx = t; idx < 3584; idx += 256) {
        int g = idx / 448, r = idx - g * 448, c = r / 56, i = r - c * 56;
        int ch = g * 16 + c;
        qn[(g * 8 + c) * 58 + i] = span[g * 896 + r] * prmQ[ch] + prmQ[128 + ch];
    }
    for (int idx = t; idx < 2240; idx += 256) {
        int row = idx / 56, i = idx - row * 56;
        int lr = (row < 8) ? (32 + row) : (row - 8);
        T[lr * 58 + i] = tab[idx];
    }
    __syncthreads();

    const int g = t >> 5, u = t & 31;
    const int half = (u < 16) ? 0 : 4;
    const float* rowA = &qn[g * 464 + (half + ((u >> 2) & 3)) * 58];
    const float* rowB = &qn[g * 464 + (half + (u & 3)) * 58];
    const float* tabS = &T[u * 58];
    const float* tabR = &T[(32 + half + (u & 3)) * 58];

    f32x2 gram2 = {0, 0}, wgt2 = {0, 0}, lin12 = {0, 0}, lin22 = {0, 0};
#pragma unroll
    for (int i = 0; i < 56; i += 2) {
        f32x2 a = *(const f32x2*)&rowA[i];
        f32x2 b2 = *(const f32x2*)&rowB[i];
        f32x2 p = a * b2;
        gram2 += p;
        wgt2 = fma2(p, *(const f32x2*)&tabS[i], wgt2);
        lin12 += b2;
        lin22 = fma2(b2, *(const f32x2*)&tabR[i], lin22);
    }
    float gram = gram2.x + gram2.y, wgt = wgt2.x + wgt2.y;
    float lin1 = lin12.x + lin12.y, lin2 = lin22.x + lin22.y;

    float linP = __shfl_xor(lin1, 16);
    float gramP = __shfl_xor(gram, 16);
    float v0 = (u < 4) ? lin1 * linP : 0.f;
    float v1 = (u < 16) ? gram * gramP : 0.f;
    float v2 = (u < 4) ? lin2 : 0.f;
    float v3 = (u < 16) ? wgt : 0.f;
    float v4 = (u >= 16 && u < 20) ? lin2 : 0.f;
    float v5 = (u >= 16) ? wgt : 0.f;
#pragma unroll
    for (int off = 16; off > 0; off >>= 1) {
        v0 += __shfl_xor(v0, off); v1 += __shfl_xor(v1, off);
        v2 += __shfl_xor(v2, off); v3 += __shfl_xor(v3, off);
        v4 += __shfl_xor(v4, off); v5 += __shfl_xor(v5, off);
    }
    if (u == 0) {
        red[g * 6 + 0] = v0; red[g * 6 + 1] = v1; red[g * 6 + 2] = v2;
        red[g * 6 + 3] = v3; red[g * 6 + 4] = v4; red[g * 6 + 5] = v5;
    }
    __syncthreads();
    if (t < 48) {
        int g2 = t / 6, s = t - g2 * 6;
        int row = ((s & 1) ? 24 : 0) + (s >> 1) * 8 + g2;
        P[(size_t)row * 1024 + b] = red[g2 * 6 + s];
    }
}

// =============== K5: fused QK/BN/exp2 -> dual-channel PV, Pm in bf16 ===============
__global__ __launch_bounds__(256) void k_main7(float* __restrict__ qkv,
                                               const float* __restrict__ rel,
                                               const float* __restrict__ tabrv,
                                               const float* __restrict__ prmQ,
                                               const float* __restrict__ prmS,
                                               float* __restrict__ P2,
                                               int useP2) {
    const int bg = blockIdx.x;
    const int g = bg & 7;
    __shared__ __align__(16) float S[16 * 60];       // q 0-3, k 4-7, v 8-15
    __shared__ __align__(16) float rall[1776];       // rq[4][111] rk[4][111] rvrev[8][111]
    __shared__ __align__(16) unsigned short Pms[56 * 72];  // bf16 exp values, 144B row stride
    __shared__ float red[128];

    const int t = threadIdx.x;
    float* span = qkv + (size_t)bg * 896;

    // ---- stage: BN'd q/k/v into S; rq/rk from rel, rvrev from tab (all f32x4) ----
    if (t < 224) {
        int e0 = t * 4;
        int c = e0 / 56, i = e0 - c * 56;
        int ch = g * 16 + c;
        float sc = prmQ[ch], sh = prmQ[128 + ch];
        float4 vv = *(const float4*)&span[e0];
        float4 o;
        o.x = vv.x * sc + sh; o.y = vv.y * sc + sh;
        o.z = vv.z * sc + sh; o.w = vv.w * sc + sh;
        *(float4*)&S[c * 60 + i] = o;
    }
    for (int idx = t; idx < 222; idx += 256)
        *(float4*)&rall[idx * 4] = *(const float4*)&rel[idx * 4];
    for (int idx = t; idx < 222; idx += 256)
        *(float4*)&rall[888 + idx * 4] = *(const float4*)&tabrv[idx * 4];
    __syncthreads();

    const int lane = t & 63, w = t >> 6;
    const int i_base = w * 14;
    const bool act = lane < 56;
    const int j = act ? lane : 0;

    const float k0 = S[240 + j], k1 = S[300 + j], k2 = S[360 + j], k3 = S[420 + j];
    const float LOG2E = 1.4426950408889634f;
    const float sc_qk = prmS[g] * LOG2E, sc_qr = prmS[8 + g] * LOG2E, sc_kr = prmS[16 + g] * LOG2E;
    const float sh_all = (prmS[24 + g] + prmS[32 + g] + prmS[40 + g]) * LOG2E;

    // ---- scores (packed row pairs) + exp2, bf16 e -> Pms ----
#pragma unroll 2
    for (int r = 0; r < 14; r += 2) {
        const int i0 = i_base + r;
        f32x2 q0 = *(const f32x2*)&S[i0];
        f32x2 q1 = *(const f32x2*)&S[60 + i0];
        f32x2 q2 = *(const f32x2*)&S[120 + i0];
        f32x2 q3 = *(const f32x2*)&S[180 + i0];
        const float* rq = &rall[i0 - j + 55];
        const float* rk = &rall[444 + j - i0 + 54];

        f32x2 qk = q0 * k0;
        qk = fma2(q1, sp2(k1), qk);
        qk = fma2(q2, sp2(k2), qk);
        qk = fma2(q3, sp2(k3), qk);

        f32x2 rq0 = {rq[0], rq[1]},     rq1 = {rq[111], rq[112]};
        f32x2 rq2 = {rq[222], rq[223]}, rq3 = {rq[333], rq[334]};
        f32x2 qr = q0 * rq0;
        qr = fma2(q1, rq1, qr);
        qr = fma2(q2, rq2, qr);
        qr = fma2(q3, rq3, qr);

        f32x2 rk0 = {rk[1], rk[0]},     rk1 = {rk[112], rk[111]};
        f32x2 rk2 = {rk[223], rk[222]}, rk3 = {rk[334], rk[333]};
        f32x2 kr = sp2(k0) * rk0;
        kr = fma2(sp2(k1), rk1, kr);
        kr = fma2(sp2(k2), rk2, kr);
        kr = fma2(sp2(k3), rk3, kr);

        f32x2 s = qk * sc_qk;
        s = fma2(qr, sp2(sc_qr), s);
        s = fma2(kr, sp2(sc_kr), s);
        s += sh_all;
        float e0 = __builtin_amdgcn_exp2f(s.x);
        float e1 = __builtin_amdgcn_exp2f(s.y);
        if (act) {
            unsigned int b0 = __float_as_uint(e0);
            unsigned int b1 = __float_as_uint(e1);
            Pms[i0 * 72 + j] = (unsigned short)((b0 + 0x8000u) >> 16);
            Pms[(i0 + 1) * 72 + j] = (unsigned short)((b1 + 0x8000u) >> 16);
        }
    }
    // no __syncthreads: each wave consumes only its own rows (DS pipe in-order)

    // ---- single-pass PV: group (cc) handles channels cc and cc+4; Pm read b128 ----
    const int il = lane & 15, cc = lane >> 4;
    const bool pact = il < 14;
    const int i = pact ? (i_base + il) : i_base;
    const int cA = cc, cB = cc + 4;

    const unsigned short* Pb = &Pms[i * 72];
    const float* vbA = &S[(8 + cA) * 60];
    const float* vbB = &S[(8 + cB) * 60];
    const float* rvA = &rall[888 + cA * 111 + 55 - i];
    const float* rvB = &rall[888 + cB * 111 + 55 - i];
    f32x4 svA = {0, 0, 0, 0}, sveA = {0, 0, 0, 0};
    f32x4 svB = {0, 0, 0, 0}, sveB = {0, 0, 0, 0};
    f32x4 rs4 = {0, 0, 0, 0};
    for (int jj = 0; jj < 56; jj += 8) {
        uint4 pu = *(const uint4*)&Pb[jj];
        f32x4 pa = {__uint_as_float(pu.x << 16), __uint_as_float(pu.x & 0xFFFF0000u),
                    __uint_as_float(pu.y << 16), __uint_as_float(pu.y & 0xFFFF0000u)};
        f32x4 pb = {__uint_as_float(pu.z << 16), __uint_as_float(pu.z & 0xFFFF0000u),
                    __uint_as_float(pu.w << 16), __uint_as_float(pu.w & 0xFFFF0000u)};
        f32x4 vA0 = *(const f32x4*)&vbA[jj],   vA1 = *(const f32x4*)&vbA[jj + 4];
        f32x4 vB0 = *(const f32x4*)&vbB[jj],   vB1 = *(const f32x4*)&vbB[jj + 4];
        f32x4 rA0 = {rvA[jj], rvA[jj + 1], rvA[jj + 2], rvA[jj + 3]};
        f32x4 rA1 = {rvA[jj + 4], rvA[jj + 5], rvA[jj + 6], rvA[jj + 7]};
        f32x4 rB0 = {rvB[jj], rvB[jj + 1], rvB[jj + 2], rvB[jj + 3]};
        f32x4 rB1 = {rvB[jj + 4], rvB[jj + 5], rvB[jj + 6], rvB[jj + 7]};
        svA = fma4(pa, vA0, svA);   svA = fma4(pb, vA1, svA);
        sveA = fma4(pa, rA0, sveA); sveA = fma4(pb, rA1, sveA);
        svB = fma4(pa, vB0, svB);   svB = fma4(pb, vB1, svB);
        sveB = fma4(pa, rB0, sveB); sveB = fma4(pb, rB1, sveB);
        rs4 += pa; rs4 += pb;
    }
    float rs = (rs4.x + rs4.y) + (rs4.z + rs4.w);
    float inv = __builtin_amdgcn_rcpf(rs);
    float sva = ((svA.x + svA.y) + (svA.z + svA.w)) * inv;
    float svea = ((sveA.x + sveA.y) + (sveA.z + sveA.w)) * inv;
    float svb = ((svB.x + svB.y) + (svB.z + svB.w)) * inv;
    float sveb = ((sveB.x + sveB.y) + (sveB.z + sveB.w)) * inv;
    if (pact) {
        span[(cA * 2) * 56 + i] = sva;
        span[(cA * 2 + 1) * 56 + i] = svea;
        span[(cB * 2) * 56 + i] = svb;
        span[(cB * 2 + 1) * 56 + i] = sveb;
    }
    // stats: 8 chains, 4-step shuffle within 16-lane groups
    float a0 = pact ? sva : 0.f,  a1 = pact ? sva * sva : 0.f;
    float a2 = pact ? svea : 0.f, a3 = pact ? svea * svea : 0.f;
    float a4 = pact ? svb : 0.f,  a5 = pact ? svb * svb : 0.f;
    float a6 = pact ? sveb : 0.f, a7 = pact ? sveb * sveb : 0.f;
#pragma unroll
    for (int off = 8; off > 0; off >>= 1) {
        a0 += __shfl_xor(a0, off); a1 += __shfl_xor(a1, off);
        a2 += __shfl_xor(a2, off); a3 += __shfl_xor(a3, off);
        a4 += __shfl_xor(a4, off); a5 += __shfl_xor(a5, off);
        a6 += __shfl_xor(a6, off); a7 += __shfl_xor(a7, off);
    }
    if (il == 0) {
        int baseA = cc * 16 + w;          // channels cc
        int baseB = (4 + cc) * 16 + w;    // channels cc+4
        red[baseA + 0]  = a0;  red[baseA + 4]  = a1;
        red[baseA + 8]  = a2;  red[baseA + 12] = a3;
        red[baseB + 0]  = a4;  red[baseB + 4]  = a5;
        red[baseB + 8]  = a6;  red[baseB + 12] = a7;
    }
    __syncthreads();
    if (useP2 && t < 32) {
        float s = red[t * 4] + red[t * 4 + 1] + red[t * 4 + 2] + red[t * 4 + 3];
        int pass = t >> 4, cc2 = (t >> 2) & 3, v = t & 3;
        int c = cc2 + (pass << 2);
        int ch = g * 16 + c * 2 + (v >> 1);
        int row = (v & 1) ? (128 + ch) : ch;
        P2[(size_t)row * 1024 + (bg >> 3)] = s;
    }
}

// =============== fallback out stats ===============
__global__ __launch_bounds__(256) void k_stats(const float* __restrict__ so,
                                               float* __restrict__ sums) {
    const int t = threadIdx.x;
    const int o = blockIdx.x >> 3;
    const int b0 = (blockIdx.x & 7) << 7;
    float s1 = 0.f, s2 = 0.f;
#pragma unroll
    for (int j = 0; j < 7; ++j) {
        int f = (j << 8) + t;
        int row = f / 14, q = f - row * 14;
        const float* src = so + ((size_t)(b0 + row) * 128 + o) * 56 + (q << 2);
        float4 v = *(const float4*)src;
        s1 += v.x + v.y + v.z + v.w;
        s2 += v.x * v.x + v.y * v.y + v.z * v.z + v.w * v.w;
    }
#pragma unroll
    for (int off = 32; off > 0; off >>= 1) { s1 += __shfl_xor(s1, off); s2 += __shfl_xor(s2, off); }
    if ((t & 63) == 0) { atomicAdd(&sums[o], s1); atomicAdd(&sums[128 + o], s2); }
}

// =============== K7: out BN + channel-pair sum + transpose ===============
__global__ __launch_bounds__(256) void k_out2(const float* __restrict__ so,
                                              const float* __restrict__ prmO,
                                              float* __restrict__ out) {
    __shared__ float L[128 * 61];
    const int t = threadIdx.x;
    const int s = blockIdx.x & 31;
    const int pc = blockIdx.x >> 5;
    const int o0 = pc << 2;
    const int p0 = pc << 1;

#pragma unroll
    for (int j = 0; j < 7; ++j) {
        int f = (j << 8) + t;
        int row = f / 14, q = f - row * 14;
        int ch = row >> 5, wcol = row & 31;
        const float* src = so + ((size_t)(s * 32 + wcol) * 128 + o0 + ch) * 56 + (q << 2);
        float4 v = *(const float4*)src;
        float* dst = &L[row * 61 + (q << 2)];
        dst[0] = v.x; dst[1] = v.y; dst[2] = v.z; dst[3] = v.w;
    }
    __syncthreads();
#pragma unroll
    for (int j = 0; j < 14; ++j) {
        int flat = (j << 8) + t;
        int wcol = flat & 31, r = flat >> 5;
        int i = r % 56, pp = r / 56;
        float v0 = L[((pp * 2) * 32 + wcol) * 61 + i];
        float v1 = L[((pp * 2 + 1) * 32 + wcol) * 61 + i];
        float sc0 = prmO[o0 + (pp << 1)],     sh0 = prmO[128 + o0 + (pp << 1)];
        float sc1 = prmO[o0 + (pp << 1) + 1], sh1 = prmO[128 + o0 + (pp << 1) + 1];
        out[(((size_t)(p0 + pp) * 32 + s) * 56 + i) * 32 + wcol] =
            v0 * sc0 + sh0 + v1 * sc1 + sh1;
    }
}

extern "C" void kernel_launch(void* const* d_in, const int* in_sizes, int n_in,
                              void* d_out, int out_size, void* d_ws, size_t ws_size,
                              hipStream_t stream) {
    const float* x     = (const float*)d_in[0];
    const float* w_qkv = (const float*)d_in[1];
    const float* g_qkv = (const float*)d_in[2];
    const float* b_qkv = (const float*)d_in[3];
    const float* g_sim = (const float*)d_in[4];
    const float* b_sim = (const float*)d_in[5];
    const float* g_out = (const float*)d_in[6];
    const float* b_out = (const float*)d_in[7];
    const float* rel   = (const float*)d_in[8];
    float* out = (float*)d_out;

    float* ws    = (float*)d_ws;
    float* qkv   = ws;
    float* Pq    = ws + 7340032;
    float* prm   = ws + 7397376;
    float* tab   = ws + 7397936;
    float* sumsO = ws + 7401064;
    float* P2    = ws + 7401472;
    const bool big = ws_size >= (size_t)(7401472 + 262144) * sizeof(float);

    k_qkv2<<<449, 256, 0, stream>>>(x, w_qkv, rel, qkv, Pq, tab);
    k_fin_red<<<128, 256, 0, stream>>>(Pq, g_qkv, b_qkv, prm, 128, 224, 1.f / 57344.f);
    k_sim2<<<1024, 256, 0, stream>>>(qkv, prm, tab, Pq);
    k_fin_red<<<24, 256, 0, stream>>>(Pq, g_sim, b_sim, prm + 256, 24, 1024, 1.f / 3211264.f);

    if (big) {
        k_main7<<<8192, 256, 0, stream>>>(qkv, rel, tab + 2240, prm, prm + 256, P2, 1);
        k_fin_red<<<128, 256, 0, stream>>>(P2, g_out, b_out, prm + 304, 128, 1024, 1.f / 57344.f);
    } else {
        hipMemsetAsync(sumsO, 0, 256 * sizeof(float), stream);
        k_main7<<<8192, 256, 0, stream>>>(qkv, rel, tab + 2240, prm, prm + 256, sumsO, 0);
        k_stats<<<1024, 256, 0, stream>>>(qkv, sumsO);
        k_fin<<<1, 128, 0, stream>>>(sumsO, g_out, b_out, prm + 304, 128, 1.f / 57344.f);
    }
    k_out2<<<1024, 256, 0, stream>>>(qkv, prm + 304, out);
}

// Round 10
// 118.647 us; speedup vs baseline: 2.5862x; 1.0926x over previous
//
#include <hip/hip_runtime.h>
#include <math.h>

#define EPS 1e-5f

typedef float f32x2 __attribute__((ext_vector_type(2)));
typedef float f32x4 __attribute__((ext_vector_type(4)));
__device__ __forceinline__ f32x2 fma2(f32x2 a, f32x2 b, f32x2 c) {
    return __builtin_elementwise_fma(a, b, c);
}
__device__ __forceinline__ f32x4 fma4(f32x4 a, f32x4 b, f32x4 c) {
    return __builtin_elementwise_fma(a, b, c);
}
__device__ __forceinline__ f32x2 sp2(float x) { f32x2 r = {x, x}; return r; }

// DPP row_shl:N add (VALU pipe, not DS). bound_ctrl=true -> OOB lanes read 0.
// row_shl accumulates downward: full 16-lane row sum lands at lane 0 of the row.
__device__ __forceinline__ float dpp_add_shl(float v, int n) {
    int x;
    switch (n) {
        case 1: x = __builtin_amdgcn_mov_dpp(__float_as_int(v), 0x101, 0xF, 0xF, true); break;
        case 2: x = __builtin_amdgcn_mov_dpp(__float_as_int(v), 0x102, 0xF, 0xF, true); break;
        case 4: x = __builtin_amdgcn_mov_dpp(__float_as_int(v), 0x104, 0xF, 0xF, true); break;
        default: x = __builtin_amdgcn_mov_dpp(__float_as_int(v), 0x108, 0xF, 0xF, true); break;
    }
    return v + __int_as_float(x);
}
// sum over each 16-lane row; result valid at lane (row base + 0)
__device__ __forceinline__ float row_sum16(float v) {
    v = dpp_add_shl(v, 1);
    v = dpp_add_shl(v, 2);
    v = dpp_add_shl(v, 4);
    v = dpp_add_shl(v, 8);
    return v;
}

// ---------------- workspace layout (floats) ----------------
// qkv   : 0          [7,340,032]  qkv, overwritten in-place with "so"
// Pq    : +7340032   [57,344]     partials: qkv [256][224], reused as sim [48][1024]
// prm   : +7397376   [560]        qkvP[256] | simP[48] | outP[256]
// tab   : +7397936   [3,128]      Rq/Rk/Sq/Sk window sums [2240] + rvrev [888]
// sumsO : +7401064   [256]        fallback out stats
// P2    : +7401472   [262,144]    out partials [256][1024]

// =============== K1: tiled GEMM (packed fp32) + transpose-write + stats;
//                 block 448 computes window-sum tables + reversed rv ===============
__global__ __launch_bounds__(256) void k_qkv2(const float* __restrict__ x,
                                              const float* __restrict__ w,
                                              const float* __restrict__ rel,
                                              float* __restrict__ qkv,
                                              float* __restrict__ P,
                                              float* __restrict__ tab) {
    __shared__ __align__(16) float X[64 * 256];
    __shared__ float T[8 * 264];
    const int t = threadIdx.x;

    if (blockIdx.x == 448) {            // ---- prep path ----
        float* r = X;
        for (int idx = t; idx < 1776; idx += 256) r[idx] = rel[idx];
        __syncthreads();
        for (int o = t; o < 2240; o += 256) {
            int row = o / 56, i = o - row * 56;
            float s = 0.f;
            if (row < 8) {
                const float* rr = &r[row * 111];
#pragma unroll
                for (int u = 0; u < 56; ++u) s += rr[i + u];
            } else if (row < 24) {
                int p = row - 8;
                const float* ra = &r[(p >> 2) * 111];
                const float* rb = &r[(p & 3) * 111];
#pragma unroll
                for (int u = 0; u < 56; ++u) s = fmaf(ra[i + u], rb[i + u], s);
            } else {
                int p = row - 24;
                const float* ra = &r[(4 + (p >> 2)) * 111];
                const float* rb = &r[(4 + (p & 3)) * 111];
#pragma unroll
                for (int u = 0; u < 56; ++u) s = fmaf(ra[i + u], rb[i + u], s);
            }
            tab[o] = s;
        }
        // reversed v-embedding rows so k_main can stage with f32x4
        for (int o = t; o < 888; o += 256) {
            int c = o / 111, u = o - c * 111;
            tab[2240 + o] = rel[888 + c * 111 + 110 - u];
        }
        return;
    }

    const int tile = blockIdx.x % 224;
    const int half = blockIdx.x / 224;
    const int m0 = tile << 8;
    const int s = m0 / 1792;
    const int i0 = (m0 - s * 1792) >> 5;

    const float* xb = x + m0;
#pragma unroll
    for (int j = 0; j < 16; ++j) {
        int f = (j << 8) + t;
        int c = f >> 6, col = (f & 63) << 2;
        *(float4*)&X[(c << 8) + col] = *(const float4*)&xb[(size_t)c * 57344 + col];
    }
    __syncthreads();

    float* qb = qkv + (size_t)s * 229376 + i0;

    for (int oc = half * 8; oc < half * 8 + 8; ++oc) {
        const int o0 = oc << 3;
        const float* wp = w + (o0 << 6);
        f32x2 a01 = {0, 0}, a23 = {0, 0}, a45 = {0, 0}, a67 = {0, 0};
        for (int c = 0; c < 64; ++c) {
            float xv = X[(c << 8) + t];
            f32x2 w01 = {wp[c], wp[64 + c]};
            f32x2 w23 = {wp[128 + c], wp[192 + c]};
            f32x2 w45 = {wp[256 + c], wp[320 + c]};
            f32x2 w67 = {wp[384 + c], wp[448 + c]};
            f32x2 xs = sp2(xv);
            a01 = fma2(w01, xs, a01);
            a23 = fma2(w23, xs, a23);
            a45 = fma2(w45, xs, a45);
            a67 = fma2(w67, xs, a67);
        }
        float accv[8] = {a01.x, a01.y, a23.x, a23.y, a45.x, a45.y, a67.x, a67.y};
        __syncthreads();
#pragma unroll
        for (int k = 0; k < 8; ++k) T[k * 264 + t + (t >> 5)] = accv[k];
        __syncthreads();
#pragma unroll
        for (int e = 0; e < 8; ++e) {
            int flat = (e << 8) + t;
            int wcol = flat >> 6, oo = (flat >> 3) & 7, il = flat & 7;
            int mm = (il << 5) + wcol;
            qb[(size_t)wcol * 7168 + (o0 + oo) * 56 + il] = T[oo * 264 + mm + (mm >> 5)];
        }
        {
            int row = t >> 5, part = t & 31;
            float s1 = 0.f, s2 = 0.f;
#pragma unroll
            for (int e = 0; e < 8; ++e) {
                int mm = (part << 3) + e;
                float v = T[row * 264 + mm + (mm >> 5)];
                s1 += v; s2 += v * v;
            }
            s1 = row_sum16(s1);
            s2 = row_sum16(s2);
            s1 += __shfl_xor(s1, 16);
            s2 += __shfl_xor(s2, 16);
            if (part == 0) {
                P[(o0 + row) * 224 + tile] = s1;
                P[(128 + o0 + row) * 224 + tile] = s2;
            }
        }
    }
}

// =============== coalesced partial reduction -> BN params ===============
__global__ __launch_bounds__(256) void k_fin_red(const float* __restrict__ P,
                                                 const float* __restrict__ g,
                                                 const float* __restrict__ bb,
                                                 float* __restrict__ prm,
                                                 int nch, int npart, float invN) {
    __shared__ float rd[8];
    const int c = blockIdx.x, t = threadIdx.x;
    const float* r1 = P + (size_t)c * npart;
    const float* r2 = P + (size_t)(nch + c) * npart;
    float s1 = 0.f, s2 = 0.f;
    for (int p = t; p < npart; p += 256) { s1 += r1[p]; s2 += r2[p]; }
#pragma unroll
    for (int off = 32; off > 0; off >>= 1) { s1 += __shfl_xor(s1, off); s2 += __shfl_xor(s2, off); }
    if ((t & 63) == 0) { rd[t >> 6] = s1; rd[4 + (t >> 6)] = s2; }
    __syncthreads();
    if (t == 0) {
        s1 = rd[0] + rd[1] + rd[2] + rd[3];
        s2 = rd[4] + rd[5] + rd[6] + rd[7];
        float m = s1 * invN;
        float v = s2 * invN - m * m;
        float sc = g[c] * rsqrtf(v + EPS);
        prm[c] = sc;
        prm[nch + c] = bb[c] - m * sc;
    }
}

// =============== small finalize (fallback out BN) ===============
__global__ void k_fin(const float* __restrict__ sums, const float* __restrict__ g,
                      const float* __restrict__ bb, float* __restrict__ prm,
                      int nch, float invN) {
    int c = threadIdx.x;
    if (c >= nch) return;
    float m = sums[c] * invN;
    float v = sums[nch + c] * invN - m * m;
    float sc = g[c] * rsqrtf(v + EPS);
    prm[c] = sc;
    prm[nch + c] = bb[c] - m * sc;
}

// =============== K3: algebraic sim statistics (packed, stride 58) ===============
__global__ __launch_bounds__(256) void k_sim2(const float* __restrict__ qkv,
                                              const float* __restrict__ prmQ,
                                              const float* __restrict__ tab,
                                              float* __restrict__ P) {
    __shared__ float qn[64 * 58];
    __shared__ float T[40 * 58];
    __shared__ float red[8 * 6];
    const int t = threadIdx.x, b = blockIdx.x;

    const float* span = qkv + (size_t)b * 7168;
    for (int idx = t; idx < 3584; idx += 256) {
        int g = idx / 448, r = idx - g * 448, c = r / 56, i = r - c * 56;
        int ch = g * 16 + c;
        qn[(g * 8 + c) * 58 + i] = span[g * 896 + r] * prmQ[ch] + prmQ[128 + ch];
    }
    for (int idx = t; idx < 2240; idx += 256) {
        int row = idx / 56, i = idx - row * 56;
        int lr = (row < 8) ? (32 + row) : (row - 8);
        T[lr * 58 + i] = tab[idx];
    }
    __syncthreads();

    const int g = t >> 5, u = t & 31;
    const int half = (u < 16) ? 0 : 4;
    const float* rowA = &qn[g * 464 + (half + ((u >> 2) & 3)) * 58];
    const float* rowB = &qn[g * 464 + (half + (u & 3)) * 58];
    const float* tabS = &T[u * 58];
    const float* tabR = &T[(32 + half + (u & 3)) * 58];

    f32x2 gram2 = {0, 0}, wgt2 = {0, 0}, lin12 = {0, 0}, lin22 = {0, 0};
#pragma unroll
    for (int i = 0; i < 56; i += 2) {
        f32x2 a = *(const f32x2*)&rowA[i];
        f32x2 b2 = *(const f32x2*)&rowB[i];
        f32x2 p = a * b2;
        gram2 += p;
        wgt2 = fma2(p, *(const f32x2*)&tabS[i], wgt2);
        lin12 += b2;
        lin22 = fma2(b2, *(const f32x2*)&tabR[i], lin22);
    }
    float gram = gram2.x + gram2.y, wgt = wgt2.x + wgt2.y;
    float lin1 = lin12.x + lin12.y, lin2 = lin22.x + lin22.y;

    float linP = __shfl_xor(lin1, 16);
    float gramP = __shfl_xor(gram, 16);
    float v0 = (u < 4) ? lin1 * linP : 0.f;
    float v1 = (u < 16) ? gram * gramP : 0.f;
    float v2 = (u < 4) ? lin2 : 0.f;
    float v3 = (u < 16) ? wgt : 0.f;
    float v4 = (u >= 16 && u < 20) ? lin2 : 0.f;
    float v5 = (u >= 16) ? wgt : 0.f;
    v0 = row_sum16(v0); v1 = row_sum16(v1); v2 = row_sum16(v2);
    v3 = row_sum16(v3); v4 = row_sum16(v4); v5 = row_sum16(v5);
    v0 += __shfl_xor(v0, 16); v1 += __shfl_xor(v1, 16);
    v2 += __shfl_xor(v2, 16); v3 += __shfl_xor(v3, 16);
    v4 += __shfl_xor(v4, 16); v5 += __shfl_xor(v5, 16);
    if (u == 0) {
        red[g * 6 + 0] = v0; red[g * 6 + 1] = v1; red[g * 6 + 2] = v2;
        red[g * 6 + 3] = v3; red[g * 6 + 4] = v4; red[g * 6 + 5] = v5;
    }
    __syncthreads();
    if (t < 48) {
        int g2 = t / 6, s = t - g2 * 6;
        int row = ((s & 1) ? 24 : 0) + (s >> 1) * 8 + g2;
        P[(size_t)row * 1024 + b] = red[g2 * 6 + s];
    }
}

// =============== K5: fused QK/BN/exp2 -> dual-channel PV, Pm in bf16,
//                 DPP stats, shift-free softmax ===============
__global__ __launch_bounds__(256) void k_main8(float* __restrict__ qkv,
                                               const float* __restrict__ rel,
                                               const float* __restrict__ tabrv,
                                               const float* __restrict__ prmQ,
                                               const float* __restrict__ prmS,
                                               float* __restrict__ P2,
                                               int useP2) {
    const int bg = blockIdx.x;
    const int g = bg & 7;
    __shared__ __align__(16) float S[16 * 60];       // q 0-3, k 4-7, v 8-15
    __shared__ __align__(16) float rall[1776];       // rq[4][111] rk[4][111] rvrev[8][111]
    __shared__ __align__(16) unsigned short Pms[56 * 72];  // bf16 exp values
    __shared__ float red[128];

    const int t = threadIdx.x;
    float* span = qkv + (size_t)bg * 896;

    // ---- stage: BN'd q/k/v into S; rq/rk from rel, rvrev from tab (all f32x4) ----
    if (t < 224) {
        int e0 = t * 4;
        int c = e0 / 56, i = e0 - c * 56;
        int ch = g * 16 + c;
        float sc = prmQ[ch], sh = prmQ[128 + ch];
        float4 vv = *(const float4*)&span[e0];
        float4 o;
        o.x = vv.x * sc + sh; o.y = vv.y * sc + sh;
        o.z = vv.z * sc + sh; o.w = vv.w * sc + sh;
        *(float4*)&S[c * 60 + i] = o;
    }
    for (int idx = t; idx < 222; idx += 256)
        *(float4*)&rall[idx * 4] = *(const float4*)&rel[idx * 4];
    for (int idx = t; idx < 222; idx += 256)
        *(float4*)&rall[888 + idx * 4] = *(const float4*)&tabrv[idx * 4];
    __syncthreads();

    const int lane = t & 63, w = t >> 6;
    const int i_base = w * 14;
    const bool act = lane < 56;
    const int j = act ? lane : 0;

    const float k0 = S[240 + j], k1 = S[300 + j], k2 = S[360 + j], k3 = S[420 + j];
    const float LOG2E = 1.4426950408889634f;
    // BN shift (sh_all) is row-uniform -> cancels exactly in softmax ratio. Dropped.
    const float sc_qk = prmS[g] * LOG2E, sc_qr = prmS[8 + g] * LOG2E, sc_kr = prmS[16 + g] * LOG2E;

    // ---- scores (packed row pairs) + exp2, bf16 e -> Pms ----
#pragma unroll 2
    for (int r = 0; r < 14; r += 2) {
        const int i0 = i_base + r;
        f32x2 q0 = *(const f32x2*)&S[i0];
        f32x2 q1 = *(const f32x2*)&S[60 + i0];
        f32x2 q2 = *(const f32x2*)&S[120 + i0];
        f32x2 q3 = *(const f32x2*)&S[180 + i0];
        const float* rq = &rall[i0 - j + 55];
        const float* rk = &rall[444 + j - i0 + 54];

        f32x2 qk = q0 * k0;
        qk = fma2(q1, sp2(k1), qk);
        qk = fma2(q2, sp2(k2), qk);
        qk = fma2(q3, sp2(k3), qk);

        f32x2 rq0 = {rq[0], rq[1]},     rq1 = {rq[111], rq[112]};
        f32x2 rq2 = {rq[222], rq[223]}, rq3 = {rq[333], rq[334]};
        f32x2 qr = q0 * rq0;
        qr = fma2(q1, rq1, qr);
        qr = fma2(q2, rq2, qr);
        qr = fma2(q3, rq3, qr);

        f32x2 rk0 = {rk[1], rk[0]},     rk1 = {rk[112], rk[111]};
        f32x2 rk2 = {rk[223], rk[222]}, rk3 = {rk[334], rk[333]};
        f32x2 kr = sp2(k0) * rk0;
        kr = fma2(sp2(k1), rk1, kr);
        kr = fma2(sp2(k2), rk2, kr);
        kr = fma2(sp2(k3), rk3, kr);

        f32x2 s = qk * sc_qk;
        s = fma2(qr, sp2(sc_qr), s);
        s = fma2(kr, sp2(sc_kr), s);
        float e0 = __builtin_amdgcn_exp2f(s.x);
        float e1 = __builtin_amdgcn_exp2f(s.y);
        if (act) {
            unsigned int b0 = __float_as_uint(e0);
            unsigned int b1 = __float_as_uint(e1);
            Pms[i0 * 72 + j] = (unsigned short)((b0 + 0x8000u) >> 16);
            Pms[(i0 + 1) * 72 + j] = (unsigned short)((b1 + 0x8000u) >> 16);
        }
    }
    // no __syncthreads: each wave consumes only its own rows (DS pipe in-order)

    // ---- single-pass PV: group (cc) handles channels cc and cc+4; Pm read b128 ----
    const int il = lane & 15, cc = lane >> 4;
    const bool pact = il < 14;
    const int i = pact ? (i_base + il) : i_base;
    const int cA = cc, cB = cc + 4;

    const unsigned short* Pb = &Pms[i * 72];
    const float* vbA = &S[(8 + cA) * 60];
    const float* vbB = &S[(8 + cB) * 60];
    const float* rvA = &rall[888 + cA * 111 + 55 - i];
    const float* rvB = &rall[888 + cB * 111 + 55 - i];
    f32x4 svA = {0, 0, 0, 0}, sveA = {0, 0, 0, 0};
    f32x4 svB = {0, 0, 0, 0}, sveB = {0, 0, 0, 0};
    f32x4 rs4 = {0, 0, 0, 0};
    for (int jj = 0; jj < 56; jj += 8) {
        uint4 pu = *(const uint4*)&Pb[jj];
        f32x4 pa = {__uint_as_float(pu.x << 16), __uint_as_float(pu.x & 0xFFFF0000u),
                    __uint_as_float(pu.y << 16), __uint_as_float(pu.y & 0xFFFF0000u)};
        f32x4 pb = {__uint_as_float(pu.z << 16), __uint_as_float(pu.z & 0xFFFF0000u),
                    __uint_as_float(pu.w << 16), __uint_as_float(pu.w & 0xFFFF0000u)};
        f32x4 vA0 = *(const f32x4*)&vbA[jj],   vA1 = *(const f32x4*)&vbA[jj + 4];
        f32x4 vB0 = *(const f32x4*)&vbB[jj],   vB1 = *(const f32x4*)&vbB[jj + 4];
        f32x4 rA0 = {rvA[jj], rvA[jj + 1], rvA[jj + 2], rvA[jj + 3]};
        f32x4 rA1 = {rvA[jj + 4], rvA[jj + 5], rvA[jj + 6], rvA[jj + 7]};
        f32x4 rB0 = {rvB[jj], rvB[jj + 1], rvB[jj + 2], rvB[jj + 3]};
        f32x4 rB1 = {rvB[jj + 4], rvB[jj + 5], rvB[jj + 6], rvB[jj + 7]};
        svA = fma4(pa, vA0, svA);   svA = fma4(pb, vA1, svA);
        sveA = fma4(pa, rA0, sveA); sveA = fma4(pb, rA1, sveA);
        svB = fma4(pa, vB0, svB);   svB = fma4(pb, vB1, svB);
        sveB = fma4(pa, rB0, sveB); sveB = fma4(pb, rB1, sveB);
        rs4 += pa; rs4 += pb;
    }
    float rs = (rs4.x + rs4.y) + (rs4.z + rs4.w);
    float inv = __builtin_amdgcn_rcpf(rs);
    float sva = ((svA.x + svA.y) + (svA.z + svA.w)) * inv;
    float svea = ((sveA.x + sveA.y) + (sveA.z + sveA.w)) * inv;
    float svb = ((svB.x + svB.y) + (svB.z + svB.w)) * inv;
    float sveb = ((sveB.x + sveB.y) + (sveB.z + sveB.w)) * inv;
    if (pact) {
        span[(cA * 2) * 56 + i] = sva;
        span[(cA * 2 + 1) * 56 + i] = svea;
        span[(cB * 2) * 56 + i] = svb;
        span[(cB * 2 + 1) * 56 + i] = sveb;
    }
    // stats: 8 chains reduced within each 16-lane row via DPP (VALU, no DS ops)
    float a0 = pact ? sva : 0.f,  a1 = pact ? sva * sva : 0.f;
    float a2 = pact ? svea : 0.f, a3 = pact ? svea * svea : 0.f;
    float a4 = pact ? svb : 0.f,  a5 = pact ? svb * svb : 0.f;
    float a6 = pact ? sveb : 0.f, a7 = pact ? sveb * sveb : 0.f;
    a0 = row_sum16(a0); a1 = row_sum16(a1); a2 = row_sum16(a2); a3 = row_sum16(a3);
    a4 = row_sum16(a4); a5 = row_sum16(a5); a6 = row_sum16(a6); a7 = row_sum16(a7);
    if (il == 0) {
        int baseA = cc * 16 + w;          // channels cc
        int baseB = (4 + cc) * 16 + w;    // channels cc+4
        red[baseA + 0]  = a0;  red[baseA + 4]  = a1;
        red[baseA + 8]  = a2;  red[baseA + 12] = a3;
        red[baseB + 0]  = a4;  red[baseB + 4]  = a5;
        red[baseB + 8]  = a6;  red[baseB + 12] = a7;
    }
    __syncthreads();
    if (useP2 && t < 32) {
        float s = red[t * 4] + red[t * 4 + 1] + red[t * 4 + 2] + red[t * 4 + 3];
        int pass = t >> 4, cc2 = (t >> 2) & 3, v = t & 3;
        int c = cc2 + (pass << 2);
        int ch = g * 16 + c * 2 + (v >> 1);
        int row = (v & 1) ? (128 + ch) : ch;
        P2[(size_t)row * 1024 + (bg >> 3)] = s;
    }
}

// =============== fallback out stats ===============
__global__ __launch_bounds__(256) void k_stats(const float* __restrict__ so,
                                               float* __restrict__ sums) {
    const int t = threadIdx.x;
    const int o = blockIdx.x >> 3;
    const int b0 = (blockIdx.x & 7) << 7;
    float s1 = 0.f, s2 = 0.f;
#pragma unroll
    for (int j = 0; j < 7; ++j) {
        int f = (j << 8) + t;
        int row = f / 14, q = f - row * 14;
        const float* src = so + ((size_t)(b0 + row) * 128 + o) * 56 + (q << 2);
        float4 v = *(const float4*)src;
        s1 += v.x + v.y + v.z + v.w;
        s2 += v.x * v.x + v.y * v.y + v.z * v.z + v.w * v.w;
    }
#pragma unroll
    for (int off = 32; off > 0; off >>= 1) { s1 += __shfl_xor(s1, off); s2 += __shfl_xor(s2, off); }
    if ((t & 63) == 0) { atomicAdd(&sums[o], s1); atomicAdd(&sums[128 + o], s2); }
}

// =============== K7: out BN + channel-pair sum + transpose ===============
__global__ __launch_bounds__(256) void k_out2(const float* __restrict__ so,
                                              const float* __restrict__ prmO,
                                              float* __restrict__ out) {
    __shared__ float L[128 * 61];
    const int t = threadIdx.x;
    const int s = blockIdx.x & 31;
    const int pc = blockIdx.x >> 5;
    const int o0 = pc << 2;
    const int p0 = pc << 1;

#pragma unroll
    for (int j = 0; j < 7; ++j) {
        int f = (j << 8) + t;
        int row = f / 14, q = f - row * 14;
        int ch = row >> 5, wcol = row & 31;
        const float* src = so + ((size_t)(s * 32 + wcol) * 128 + o0 + ch) * 56 + (q << 2);
        float4 v = *(const float4*)src;
        float* dst = &L[row * 61 + (q << 2)];
        dst[0] = v.x; dst[1] = v.y; dst[2] = v.z; dst[3] = v.w;
    }
    __syncthreads();
#pragma unroll
    for (int j = 0; j < 14; ++j) {
        int flat = (j << 8) + t;
        int wcol = flat & 31, r = flat >> 5;
        int i = r % 56, pp = r / 56;
        float v0 = L[((pp * 2) * 32 + wcol) * 61 + i];
        float v1 = L[((pp * 2 + 1) * 32 + wcol) * 61 + i];
        float sc0 = prmO[o0 + (pp << 1)],     sh0 = prmO[128 + o0 + (pp << 1)];
        float sc1 = prmO[o0 + (pp << 1) + 1], sh1 = prmO[128 + o0 + (pp << 1) + 1];
        out[(((size_t)(p0 + pp) * 32 + s) * 56 + i) * 32 + wcol] =
            v0 * sc0 + sh0 + v1 * sc1 + sh1;
    }
}

extern "C" void kernel_launch(void* const* d_in, const int* in_sizes, int n_in,
                              void* d_out, int out_size, void* d_ws, size_t ws_size,
                              hipStream_t stream) {
    const float* x     = (const float*)d_in[0];
    const float* w_qkv = (const float*)d_in[1];
    const float* g_qkv = (const float*)d_in[2];
    const float* b_qkv = (const float*)d_in[3];
    const float* g_sim = (const float*)d_in[4];
    const float* b_sim = (const float*)d_in[5];
    const float* g_out = (const float*)d_in[6];
    const float* b_out = (const float*)d_in[7];
    const float* rel   = (const float*)d_in[8];
    float* out = (float*)d_out;

    float* ws    = (float*)d_ws;
    float* qkv   = ws;
    float* Pq    = ws + 7340032;
    float* prm   = ws + 7397376;
    float* tab   = ws + 7397936;
    float* sumsO = ws + 7401064;
    float* P2    = ws + 7401472;
    const bool big = ws_size >= (size_t)(7401472 + 262144) * sizeof(float);

    k_qkv2<<<449, 256, 0, stream>>>(x, w_qkv, rel, qkv, Pq, tab);
    k_fin_red<<<128, 256, 0, stream>>>(Pq, g_qkv, b_qkv, prm, 128, 224, 1.f / 57344.f);
    k_sim2<<<1024, 256, 0, stream>>>(qkv, prm, tab, Pq);
    k_fin_red<<<24, 256, 0, stream>>>(Pq, g_sim, b_sim, prm + 256, 24, 1024, 1.f / 3211264.f);

    if (big) {
        k_main8<<<8192, 256, 0, stream>>>(qkv, rel, tab + 2240, prm, prm + 256, P2, 1);
        k_fin_red<<<128, 256, 0, stream>>>(P2, g_out, b_out, prm + 304, 128, 1024, 1.f / 57344.f);
    } else {
        hipMemsetAsync(sumsO, 0, 256 * sizeof(float), stream);
        k_main8<<<8192, 256, 0, stream>>>(qkv, rel, tab + 2240, prm, prm + 256, sumsO, 0);
        k_stats<<<1024, 256, 0, stream>>>(qkv, sumsO);
        k_fin<<<1, 128, 0, stream>>>(sumsO, g_out, b_out, prm + 304, 128, 1.f / 57344.f);
    }
    k_out2<<<1024, 256, 0, stream>>>(qkv, prm + 304, out);
}